// Round 6
// baseline (264.921 us; speedup 1.0000x reference)
//
#include <hip/hip_runtime.h>

typedef unsigned short u16;
typedef unsigned int u32;
typedef __bf16 bf16x8 __attribute__((ext_vector_type(8)));
typedef float f32x4 __attribute__((ext_vector_type(4)));
typedef float f32x16 __attribute__((ext_vector_type(16)));
typedef u32 u32x4 __attribute__((ext_vector_type(4)));

#define MFMA_BF16(a, b, c) __builtin_amdgcn_mfma_f32_16x16x32_bf16((a), (b), (c), 0, 0, 0)
#define MFMA32(a, b, c) __builtin_amdgcn_mfma_f32_32x32x16_bf16((a), (b), (c), 0, 0, 0)

// log2-domain constant: 0.125 * log2(e), folded into w_qkv Q-rows at prep
#define QSCALE 0.18033688011112042f

#define BARRIER __builtin_amdgcn_s_barrier()
#define LGKM0                                                \
  do {                                                       \
    asm volatile("s_waitcnt lgkmcnt(0)" ::: "memory");       \
    __builtin_amdgcn_sched_barrier(0);                       \
  } while (0)
#define WAIT_VM(N) asm volatile("s_waitcnt vmcnt(" #N ")" ::: "memory")

// ---------- helpers ----------

__device__ __forceinline__ u16 f2bf(float f) {
  u32 u = __builtin_bit_cast(u32, f);
  u += 0x7fffu + ((u >> 16) & 1u);   // RNE
  return (u16)(u >> 16);
}

__device__ __forceinline__ void async_copy16(const void* g, void* l) {
  __builtin_amdgcn_global_load_lds(
      (__attribute__((address_space(1))) void*)g,
      (__attribute__((address_space(3))) void*)l, 16, 0, 0);
}

__device__ __forceinline__ u32 cvt_pk_bf16(float lo, float hi) {
  u32 d;
  asm("v_cvt_pk_bf16_f32 %0, %1, %2" : "=v"(d) : "v"(lo), "v"(hi));
  return d;
}

__device__ __forceinline__ void swap32(u32& a, u32& b) {
  asm("v_permlane32_swap_b32 %0, %1" : "+v"(a), "+v"(b));
}

// ---------- kernel 0: fused fp32->bf16 converts + RoPE cos/sin table ----------

__global__ __launch_bounds__(256) void prep_kernel(
    const float* __restrict__ x_f, const float* __restrict__ wqkv_f,
    const float* __restrict__ wo_f, u16* __restrict__ xb,
    u16* __restrict__ wqkvb, u16* __restrict__ wob, float2* __restrict__ rope_t) {
  const int blk = blockIdx.x;
  if (blk < 12288) {
    const float* src;
    u16* dst;
    int base;
    float scale = 1.0f;
    if (blk < 8192)      { src = x_f;    dst = xb;    base = blk; }
    else if (blk < 11264){ src = wqkv_f; dst = wqkvb; base = blk - 8192;
                           if (base < 1024) scale = QSCALE; }  // Q rows
    else                 { src = wo_f;   dst = wob;   base = blk - 11264; }
    const int i = base * 1024 + threadIdx.x * 4;
    const float4 v = *(const float4*)(src + i);
    ushort4 o;
    o.x = f2bf(v.x * scale); o.y = f2bf(v.y * scale);
    o.z = f2bf(v.z * scale); o.w = f2bf(v.w * scale);
    *(ushort4*)(dst + i) = o;
  } else {
    const int idx = (blk - 12288) * 256 + threadIdx.x;  // [0, 65536)
    const int s = idx >> 5, i = idx & 31;
    const float invf = __builtin_amdgcn_exp2f(-(float)i * 0.41524101186092027f);
    float rev = (float)s * invf * 0.15915494309189535f;  // radians -> revolutions
    rev -= floorf(rev);
    rope_t[idx] = make_float2(__builtin_amdgcn_cosf(rev), __builtin_amdgcn_sinf(rev));
  }
}

// ---------- 256x256 GEMM-BT core (m201 geometry): per-wave 128x64 -----------
// 512 thr = 8 waves (2M x 4N); acc[8][4]; BK=64; LDS 128 KB dbuf.
// 4 phases/K-tile x 16 MFMA, pre+post barriers; tile-end burst staging of
// tile t+2 into the buffer whose reads just completed; WAIT_VM(8) counted
// (t+1's 8 loads retired; t+2's 8 stay in flight across the whole next tile).
// XOR granule swizzle (g ^= row&7) on source + read (involution, rule #21).

__device__ __forceinline__ void gemm256sq(const u16* __restrict__ A,
                                          const u16* __restrict__ B,
                                          int row0, int col0, u16* lds,
                                          f32x4 acc[8][4]) {
  const int tid = threadIdx.x;
  const int wave = tid >> 6, lane = tid & 63;
  const int fr = lane & 15, quad = lane >> 4;
  const int wr = wave >> 2, wc = wave & 3;
  const int wm = wr * 128, wn = wc * 64;

  f32x4 zero = {0.f, 0.f, 0.f, 0.f};
#pragma unroll
  for (int mt = 0; mt < 8; ++mt)
#pragma unroll
    for (int nt = 0; nt < 4; ++nt) acc[mt][nt] = zero;

  // staging: tile t -> buf (t&1). A tile 256x64 (32 KB, 4 insts), B same.
  auto stage = [&](int t) {
    u16* ba = lds + ((t & 1) ? 32768 : 0);
    u16* bb = lds + ((t & 1) ? 49152 : 16384);
    const int k0 = t * 64;
#pragma unroll
    for (int it = 0; it < 4; ++it) {
      const int slot = it * 512 + tid;
      const int row = slot >> 3, g = slot & 7;
      const int gs = (g ^ (row & 7)) * 8;
      async_copy16(A + (size_t)(row0 + row) * 1024 + k0 + gs, ba + slot * 8);
    }
#pragma unroll
    for (int it = 0; it < 4; ++it) {
      const int slot = it * 512 + tid;
      const int row = slot >> 3, g = slot & 7;
      const int gs = (g ^ (row & 7)) * 8;
      async_copy16(B + (size_t)(col0 + row) * 1024 + k0 + gs, bb + slot * 8);
    }
  };

  const int swr = fr & 7;
  const int sw0 = (quad ^ swr) * 8;         // k granule 0..3 (kk=0)
  const int sw1 = ((quad + 4) ^ swr) * 8;   // k granule 4..7 (kk=1)

  stage(0);
  stage(1);
  WAIT_VM(8);   // tile 0 resident
  BARRIER;

  for (int t = 0; t < 16; ++t) {
    const u16* ba = lds + ((t & 1) ? 32768 : 0);
    const u16* bb = lds + ((t & 1) ? 49152 : 16384);

    // ---- phase 0: read a0-3 (x2kk) + b0-1 (x2kk); MFMA m0-3 x n0-1 ----
    bf16x8 a0k0 = *(const bf16x8*)(ba + (wm + fr) * 64 + sw0);
    bf16x8 a0k1 = *(const bf16x8*)(ba + (wm + fr) * 64 + sw1);
    bf16x8 a1k0 = *(const bf16x8*)(ba + (wm + 16 + fr) * 64 + sw0);
    bf16x8 a1k1 = *(const bf16x8*)(ba + (wm + 16 + fr) * 64 + sw1);
    bf16x8 a2k0 = *(const bf16x8*)(ba + (wm + 32 + fr) * 64 + sw0);
    bf16x8 a2k1 = *(const bf16x8*)(ba + (wm + 32 + fr) * 64 + sw1);
    bf16x8 a3k0 = *(const bf16x8*)(ba + (wm + 48 + fr) * 64 + sw0);
    bf16x8 a3k1 = *(const bf16x8*)(ba + (wm + 48 + fr) * 64 + sw1);
    bf16x8 b0k0 = *(const bf16x8*)(bb + (wn + fr) * 64 + sw0);
    bf16x8 b0k1 = *(const bf16x8*)(bb + (wn + fr) * 64 + sw1);
    bf16x8 b1k0 = *(const bf16x8*)(bb + (wn + 16 + fr) * 64 + sw0);
    bf16x8 b1k1 = *(const bf16x8*)(bb + (wn + 16 + fr) * 64 + sw1);
    BARRIER;
    LGKM0;
    __builtin_amdgcn_s_setprio(1);
    acc[0][0] = MFMA_BF16(a0k0, b0k0, acc[0][0]);
    acc[0][1] = MFMA_BF16(a0k0, b1k0, acc[0][1]);
    acc[1][0] = MFMA_BF16(a1k0, b0k0, acc[1][0]);
    acc[1][1] = MFMA_BF16(a1k0, b1k0, acc[1][1]);
    acc[2][0] = MFMA_BF16(a2k0, b0k0, acc[2][0]);
    acc[2][1] = MFMA_BF16(a2k0, b1k0, acc[2][1]);
    acc[3][0] = MFMA_BF16(a3k0, b0k0, acc[3][0]);
    acc[3][1] = MFMA_BF16(a3k0, b1k0, acc[3][1]);
    acc[0][0] = MFMA_BF16(a0k1, b0k1, acc[0][0]);
    acc[0][1] = MFMA_BF16(a0k1, b1k1, acc[0][1]);
    acc[1][0] = MFMA_BF16(a1k1, b0k1, acc[1][0]);
    acc[1][1] = MFMA_BF16(a1k1, b1k1, acc[1][1]);
    acc[2][0] = MFMA_BF16(a2k1, b0k1, acc[2][0]);
    acc[2][1] = MFMA_BF16(a2k1, b1k1, acc[2][1]);
    acc[3][0] = MFMA_BF16(a3k1, b0k1, acc[3][0]);
    acc[3][1] = MFMA_BF16(a3k1, b1k1, acc[3][1]);
    __builtin_amdgcn_s_setprio(0);
    BARRIER;

    // ---- phase 1: read b2-3 (x2kk); MFMA m0-3 x n2-3 ----
    bf16x8 b2k0 = *(const bf16x8*)(bb + (wn + 32 + fr) * 64 + sw0);
    bf16x8 b2k1 = *(const bf16x8*)(bb + (wn + 32 + fr) * 64 + sw1);
    bf16x8 b3k0 = *(const bf16x8*)(bb + (wn + 48 + fr) * 64 + sw0);
    bf16x8 b3k1 = *(const bf16x8*)(bb + (wn + 48 + fr) * 64 + sw1);
    BARRIER;
    LGKM0;
    __builtin_amdgcn_s_setprio(1);
    acc[0][2] = MFMA_BF16(a0k0, b2k0, acc[0][2]);
    acc[0][3] = MFMA_BF16(a0k0, b3k0, acc[0][3]);
    acc[1][2] = MFMA_BF16(a1k0, b2k0, acc[1][2]);
    acc[1][3] = MFMA_BF16(a1k0, b3k0, acc[1][3]);
    acc[2][2] = MFMA_BF16(a2k0, b2k0, acc[2][2]);
    acc[2][3] = MFMA_BF16(a2k0, b3k0, acc[2][3]);
    acc[3][2] = MFMA_BF16(a3k0, b2k0, acc[3][2]);
    acc[3][3] = MFMA_BF16(a3k0, b3k0, acc[3][3]);
    acc[0][2] = MFMA_BF16(a0k1, b2k1, acc[0][2]);
    acc[0][3] = MFMA_BF16(a0k1, b3k1, acc[0][3]);
    acc[1][2] = MFMA_BF16(a1k1, b2k1, acc[1][2]);
    acc[1][3] = MFMA_BF16(a1k1, b3k1, acc[1][3]);
    acc[2][2] = MFMA_BF16(a2k1, b2k1, acc[2][2]);
    acc[2][3] = MFMA_BF16(a2k1, b3k1, acc[2][3]);
    acc[3][2] = MFMA_BF16(a3k1, b2k1, acc[3][2]);
    acc[3][3] = MFMA_BF16(a3k1, b3k1, acc[3][3]);
    __builtin_amdgcn_s_setprio(0);
    BARRIER;

    // ---- phase 2: read a4-7 (x2kk); MFMA m4-7 x n0-1 ----
    bf16x8 a4k0 = *(const bf16x8*)(ba + (wm + 64 + fr) * 64 + sw0);
    bf16x8 a4k1 = *(const bf16x8*)(ba + (wm + 64 + fr) * 64 + sw1);
    bf16x8 a5k0 = *(const bf16x8*)(ba + (wm + 80 + fr) * 64 + sw0);
    bf16x8 a5k1 = *(const bf16x8*)(ba + (wm + 80 + fr) * 64 + sw1);
    bf16x8 a6k0 = *(const bf16x8*)(ba + (wm + 96 + fr) * 64 + sw0);
    bf16x8 a6k1 = *(const bf16x8*)(ba + (wm + 96 + fr) * 64 + sw1);
    bf16x8 a7k0 = *(const bf16x8*)(ba + (wm + 112 + fr) * 64 + sw0);
    bf16x8 a7k1 = *(const bf16x8*)(ba + (wm + 112 + fr) * 64 + sw1);
    BARRIER;
    LGKM0;
    __builtin_amdgcn_s_setprio(1);
    acc[4][0] = MFMA_BF16(a4k0, b0k0, acc[4][0]);
    acc[4][1] = MFMA_BF16(a4k0, b1k0, acc[4][1]);
    acc[5][0] = MFMA_BF16(a5k0, b0k0, acc[5][0]);
    acc[5][1] = MFMA_BF16(a5k0, b1k0, acc[5][1]);
    acc[6][0] = MFMA_BF16(a6k0, b0k0, acc[6][0]);
    acc[6][1] = MFMA_BF16(a6k0, b1k0, acc[6][1]);
    acc[7][0] = MFMA_BF16(a7k0, b0k0, acc[7][0]);
    acc[7][1] = MFMA_BF16(a7k0, b1k0, acc[7][1]);
    acc[4][0] = MFMA_BF16(a4k1, b0k1, acc[4][0]);
    acc[4][1] = MFMA_BF16(a4k1, b1k1, acc[4][1]);
    acc[5][0] = MFMA_BF16(a5k1, b0k1, acc[5][0]);
    acc[5][1] = MFMA_BF16(a5k1, b1k1, acc[5][1]);
    acc[6][0] = MFMA_BF16(a6k1, b0k1, acc[6][0]);
    acc[6][1] = MFMA_BF16(a6k1, b1k1, acc[6][1]);
    acc[7][0] = MFMA_BF16(a7k1, b0k1, acc[7][0]);
    acc[7][1] = MFMA_BF16(a7k1, b1k1, acc[7][1]);
    __builtin_amdgcn_s_setprio(0);
    BARRIER;

    // ---- phase 3: no new reads; MFMA m4-7 x n2-3 ----
    __builtin_amdgcn_s_setprio(1);
    acc[4][2] = MFMA_BF16(a4k0, b2k0, acc[4][2]);
    acc[4][3] = MFMA_BF16(a4k0, b3k0, acc[4][3]);
    acc[5][2] = MFMA_BF16(a5k0, b2k0, acc[5][2]);
    acc[5][3] = MFMA_BF16(a5k0, b3k0, acc[5][3]);
    acc[6][2] = MFMA_BF16(a6k0, b2k0, acc[6][2]);
    acc[6][3] = MFMA_BF16(a6k0, b3k0, acc[6][3]);
    acc[7][2] = MFMA_BF16(a7k0, b2k0, acc[7][2]);
    acc[7][3] = MFMA_BF16(a7k0, b3k0, acc[7][3]);
    acc[4][2] = MFMA_BF16(a4k1, b2k1, acc[4][2]);
    acc[4][3] = MFMA_BF16(a4k1, b3k1, acc[4][3]);
    acc[5][2] = MFMA_BF16(a5k1, b2k1, acc[5][2]);
    acc[5][3] = MFMA_BF16(a5k1, b3k1, acc[5][3]);
    acc[6][2] = MFMA_BF16(a6k1, b2k1, acc[6][2]);
    acc[6][3] = MFMA_BF16(a6k1, b3k1, acc[6][3]);
    acc[7][2] = MFMA_BF16(a7k1, b2k1, acc[7][2]);
    acc[7][3] = MFMA_BF16(a7k1, b3k1, acc[7][3]);
    __builtin_amdgcn_s_setprio(0);

    // ---- tile end: all reads of buf[t&1] done after this barrier ----
    BARRIER;
    if (t + 2 < 16) {
      stage(t + 2);          // into buf[t&1] (reads just completed)
      WAIT_VM(8);            // tile t+1 resident; t+2's 8 loads in flight
    } else {
      WAIT_VM(0);            // epilogue drain (cheap at t=15)
    }
    BARRIER;
  }
}

// ---------- kernel 1: QKV projection + RoPE, 2-pass coalesced epilogue -------
// 256x256 tiles: grid (12, 32) = 384 blocks (2 rounds at 1 block/CU).

__global__ __launch_bounds__(512, 2) void qkv_rope_kernel(
    const u16* __restrict__ x, const u16* __restrict__ w_qkv,
    const float2* __restrict__ rope_t,
    u16* __restrict__ q_ws, u16* __restrict__ k_ws, u16* __restrict__ vt_ws) {
  __shared__ u16 lds[65536];  // 128 KB: gemm dbuf; epilogue reuses it
  f32x4 acc[8][4];
  const int row0 = blockIdx.y * 256;  // M = 8192
  const int col0 = blockIdx.x * 256;  // N = 3072
  gemm256sq(x, w_qkv, row0, col0, lds, acc);

  const int tid = threadIdx.x;
  const int wave = tid >> 6, lane = tid & 63;
  const int fr = lane & 15, quad = lane >> 4;
  const int wr = wave >> 2, wc = wave & 3;
  const int wm = wr * 128;
  const int region = col0 >> 10;      // 0=Q 1=K 2=V (block-uniform; 1024%256==0)
  const int f0 = col0 & 1023;
  const int s0r = row0 & 2047;
  const int bb = row0 >> 11;
  const int h0 = f0 >> 6;             // block covers heads h0 .. h0+3

  // two 128-col passes so the stage buffer fits in 128 KB LDS
#pragma unroll
  for (int hp = 0; hp < 2; ++hp) {
    __syncthreads();
    if ((wc >> 1) == hp) {
      const int n1b = (wc & 1) * 64;
      if (region < 2) {
        // rotate in registers, stage [m 256][n1 128] (stride 136)
#pragma unroll
        for (int mt = 0; mt < 8; ++mt)
#pragma unroll
          for (int nt = 0; nt < 4; ++nt) {
            const int n1 = n1b + nt * 16 + fr;
            const int d = n1 & 63;
#pragma unroll
            for (int r = 0; r < 4; ++r) {
              const int m = wm + mt * 16 + quad * 4 + r;
              const float own = acc[mt][nt][r];
              const float part = __shfl_xor(own, 1);
              const float2 cssn = rope_t[(s0r + m) * 32 + (d >> 1)];
              const float val = (d & 1) ? (part * cssn.y + own * cssn.x)
                                        : (own * cssn.x - part * cssn.y);
              lds[m * 136 + n1] = f2bf(val);
            }
          }
      } else {
        // stage transposed [n1 128][m 256] (stride 264)
#pragma unroll
        for (int mt = 0; mt < 8; ++mt)
#pragma unroll
          for (int nt = 0; nt < 4; ++nt) {
            const int n1 = n1b + nt * 16 + fr;
#pragma unroll
            for (int r = 0; r < 4; ++r) {
              const int m = wm + mt * 16 + quad * 4 + r;
              lds[n1 * 264 + m] = f2bf(acc[mt][nt][r]);
            }
          }
      }
    }
    __syncthreads();
    if (region < 2) {
      u16* dst = (region == 0) ? q_ws : k_ws;
#pragma unroll
      for (int j = 0; j < 8; ++j) {
        const int idx2 = j * 512 + tid;       // 0..4095
        const int m = idx2 >> 4;              // 0..255
        const int rem = idx2 & 15;
        const int hf = rem >> 3;              // head half within pass
        const int c8 = (rem & 7) * 8;
        const uint4 v = *(const uint4*)(lds + m * 136 + hf * 64 + c8);
        *(uint4*)(dst + ((size_t)(bb * 16 + h0 + hp * 2 + hf) * 2048 + s0r + m) * 64 +
                  c8) = v;
      }
    } else {
#pragma unroll
      for (int j = 0; j < 8; ++j) {
        const int idx2 = j * 512 + tid;       // 0..4095
        const int n1 = idx2 >> 5;             // 0..127
        const int mc = (idx2 & 31) * 8;       // 0..248
        const int ng = hp * 128 + n1;
        const int h = h0 + (ng >> 6);
        const int d = ng & 63;
        const uint4 v = *(const uint4*)(lds + n1 * 264 + mc);
        *(uint4*)(vt_ws + ((size_t)(bb * 16 + h) * 64 + d) * 2048 + s0r + mc) = v;
      }
    }
  }
}

// ---------- 256x128 GEMM-BT core (r2 structure) — used by oproj ----------

__device__ __forceinline__ void gemm256_bt(const u16* __restrict__ A,
                                           const u16* __restrict__ B,
                                           int row0, int col0, u16* lds,
                                           f32x4 acc[4][4]) {
  const int tid = threadIdx.x;
  const int wave = tid >> 6, lane = tid & 63;
  const int fr = lane & 15, quad = lane >> 4;
  const int wm = (wave >> 1) * 64;   // 0,64,128,192
  const int wn = (wave & 1) * 64;    // 0,64
  u16* bufA0 = lds;                  // [256][64]
  u16* bufB0 = lds + 16384;          // [128][64]
  u16* bufA1 = lds + 24576;
  u16* bufB1 = lds + 40960;

  const int l8 = lane >> 3, l7 = lane & 7;
  const int csw = (l7 ^ l8) * 8;     // pre-swizzled source col (l8 < 8)

  f32x4 zero = {0.f, 0.f, 0.f, 0.f};
#pragma unroll
  for (int mt = 0; mt < 4; ++mt)
#pragma unroll
    for (int nt = 0; nt < 4; ++nt) acc[mt][nt] = zero;

  auto stage = [&](int t) {
    u16* ba = (t & 1) ? bufA1 : bufA0;
    u16* bb = (t & 1) ? bufB1 : bufB0;
    const int k0 = t * 64;
#pragma unroll
    for (int c = 0; c < 4; ++c) {
      const int ch = c * 8 + wave;   // 0..31 -> rows [ch*8, ch*8+8)
      async_copy16(A + (size_t)(row0 + ch * 8 + l8) * 1024 + k0 + csw,
                   ba + ch * 512);
    }
#pragma unroll
    for (int c = 0; c < 2; ++c) {
      const int ch = c * 8 + wave;   // 0..15
      async_copy16(B + (size_t)(col0 + ch * 8 + l8) * 1024 + k0 + csw,
                   bb + ch * 512);
    }
  };

  const int f7 = fr & 7;
  const int sw0 = (quad ^ f7) * 8;         // kk = 0
  const int sw1 = ((quad + 4) ^ f7) * 8;   // kk = 1
  const int ar0 = (wm + fr) * 64, ar1 = (wm + 16 + fr) * 64;
  const int ar2 = (wm + 32 + fr) * 64, ar3 = (wm + 48 + fr) * 64;
  const int br0 = (wn + fr) * 64, br1 = (wn + 16 + fr) * 64;
  const int br2 = (wn + 32 + fr) * 64, br3 = (wn + 48 + fr) * 64;

  stage(0);
  stage(1);
  WAIT_VM(6);
  BARRIER;

  for (int t = 0; t < 16; ++t) {
    const u16* ba = (t & 1) ? bufA1 : bufA0;
    const u16* bb = (t & 1) ? bufB1 : bufB0;

    bf16x8 a0k0 = *(const bf16x8*)(ba + ar0 + sw0);
    bf16x8 a0k1 = *(const bf16x8*)(ba + ar0 + sw1);
    bf16x8 a1k0 = *(const bf16x8*)(ba + ar1 + sw0);
    bf16x8 a1k1 = *(const bf16x8*)(ba + ar1 + sw1);
    bf16x8 b0k0 = *(const bf16x8*)(bb + br0 + sw0);
    bf16x8 b0k1 = *(const bf16x8*)(bb + br0 + sw1);
    bf16x8 b1k0 = *(const bf16x8*)(bb + br1 + sw0);
    bf16x8 b1k1 = *(const bf16x8*)(bb + br1 + sw1);
    BARRIER;
    LGKM0;
    __builtin_amdgcn_s_setprio(1);
    acc[0][0] = MFMA_BF16(a0k0, b0k0, acc[0][0]);
    acc[0][1] = MFMA_BF16(a0k0, b1k0, acc[0][1]);
    acc[1][0] = MFMA_BF16(a1k0, b0k0, acc[1][0]);
    acc[1][1] = MFMA_BF16(a1k0, b1k0, acc[1][1]);
    acc[0][0] = MFMA_BF16(a0k1, b0k1, acc[0][0]);
    acc[0][1] = MFMA_BF16(a0k1, b1k1, acc[0][1]);
    acc[1][0] = MFMA_BF16(a1k1, b0k1, acc[1][0]);
    acc[1][1] = MFMA_BF16(a1k1, b1k1, acc[1][1]);
    __builtin_amdgcn_s_setprio(0);
    BARRIER;

    bf16x8 b2k0 = *(const bf16x8*)(bb + br2 + sw0);
    bf16x8 b2k1 = *(const bf16x8*)(bb + br2 + sw1);
    bf16x8 b3k0 = *(const bf16x8*)(bb + br3 + sw0);
    bf16x8 b3k1 = *(const bf16x8*)(bb + br3 + sw1);
    BARRIER;
    LGKM0;
    __builtin_amdgcn_s_setprio(1);
    acc[0][2] = MFMA_BF16(a0k0, b2k0, acc[0][2]);
    acc[0][3] = MFMA_BF16(a0k0, b3k0, acc[0][3]);
    acc[1][2] = MFMA_BF16(a1k0, b2k0, acc[1][2]);
    acc[1][3] = MFMA_BF16(a1k0, b3k0, acc[1][3]);
    acc[0][2] = MFMA_BF16(a0k1, b2k1, acc[0][2]);
    acc[0][3] = MFMA_BF16(a0k1, b3k1, acc[0][3]);
    acc[1][2] = MFMA_BF16(a1k1, b2k1, acc[1][2]);
    acc[1][3] = MFMA_BF16(a1k1, b3k1, acc[1][3]);
    __builtin_amdgcn_s_setprio(0);
    BARRIER;

    bf16x8 a2k0 = *(const bf16x8*)(ba + ar2 + sw0);
    bf16x8 a2k1 = *(const bf16x8*)(ba + ar2 + sw1);
    bf16x8 a3k0 = *(const bf16x8*)(ba + ar3 + sw0);
    bf16x8 a3k1 = *(const bf16x8*)(ba + ar3 + sw1);
    BARRIER;
    LGKM0;
    __builtin_amdgcn_s_setprio(1);
    acc[2][0] = MFMA_BF16(a2k0, b0k0, acc[2][0]);
    acc[2][1] = MFMA_BF16(a2k0, b1k0, acc[2][1]);
    acc[3][0] = MFMA_BF16(a3k0, b0k0, acc[3][0]);
    acc[3][1] = MFMA_BF16(a3k0, b1k0, acc[3][1]);
    acc[2][0] = MFMA_BF16(a2k1, b0k1, acc[2][0]);
    acc[2][1] = MFMA_BF16(a2k1, b1k1, acc[2][1]);
    acc[3][0] = MFMA_BF16(a3k1, b0k1, acc[3][0]);
    acc[3][1] = MFMA_BF16(a3k1, b1k1, acc[3][1]);
    acc[2][2] = MFMA_BF16(a2k0, b2k0, acc[2][2]);
    acc[2][3] = MFMA_BF16(a2k0, b3k0, acc[2][3]);
    acc[3][2] = MFMA_BF16(a3k0, b2k0, acc[3][2]);
    acc[3][3] = MFMA_BF16(a3k0, b3k0, acc[3][3]);
    acc[2][2] = MFMA_BF16(a2k1, b2k1, acc[2][2]);
    acc[2][3] = MFMA_BF16(a2k1, b3k1, acc[2][3]);
    acc[3][2] = MFMA_BF16(a3k1, b2k1, acc[3][2]);
    acc[3][3] = MFMA_BF16(a3k1, b3k1, acc[3][3]);
    __builtin_amdgcn_s_setprio(0);

    BARRIER;
    if (t + 2 < 16) {
      stage(t + 2);
      WAIT_VM(6);
    } else if (t + 2 == 16) {
      WAIT_VM(0);
    }
    BARRIER;
  }
}

// ---------- kernel 2: causal flash attention, swapped-QK 32x32 in-reg softmax -
// (verified r3 structure, unchanged)

__global__ __launch_bounds__(256, 3) void flash_attn_kernel(
    const u16* __restrict__ Q, const u16* __restrict__ K, const u16* __restrict__ Vt,
    const int* __restrict__ pad, u16* __restrict__ O) {
  const int S = 2048;
  const int idx = blockIdx.x;
  const int bh = idx & 63;
  const int b = bh >> 4, h = bh & 15;
  // balanced q-tile remap: perm = [[0,1,2,3],[7,6,5,4],[8,9,10,11],[15,14,13,12]]
  const int j = (idx >> 6) & 3;
  const int sr = idx >> 8;
  const int qt_rev = (sr >> 1) * 8 + ((sr & 1) ? (7 - j) : j);
  const int q0 = (15 - qt_rev) * 128;
  const u16* Qh = Q + (size_t)bh * S * 64;
  const u16* Kh = K + (size_t)bh * S * 64;
  const u16* Vth = Vt + (size_t)bh * 64 * S;
  const int tid = threadIdx.x, wave = tid >> 6, lane = tid & 63;
  const int l31 = lane & 31, hi = lane >> 5, l7 = lane & 7;

  __shared__ u16 lds_k[2][64 * 64];    // dbuf [kpos 64][d 64] swizzled  16 KB
  __shared__ u16 lds_vt[2][64 * 64];   // dbuf [d 64][kpos 64] swizzled  16 KB
  __shared__ float lds_biasf[2][64];   // {0, -inf} per kpos             512 B

  const int qb = q0 + wave * 32;  // wave's first q row

  // Q as B-operand: lane holds Q[qb + l31][d = c*16 + hi*8 + 0..7]
  bf16x8 qfrag[4];
#pragma unroll
  for (int c = 0; c < 4; ++c)
    qfrag[c] = *(const bf16x8*)(Qh + (size_t)(qb + l31) * 64 + c * 16 + hi * 8);

  bf16x8 ones;
#pragma unroll
  for (int jj = 0; jj < 8; ++jj) ones[jj] = (__bf16)1.0f;

  f32x16 o_acc0, o_acc1, lacc;
#pragma unroll
  for (int r = 0; r < 16; ++r) { o_acc0[r] = 0.f; o_acc1[r] = 0.f; lacc[r] = 0.f; }

  const float NEG = -__builtin_inff();
  int pv0 = 1, pv1 = 1;

  auto stage = [&](int k0, int bufi) {
#pragma unroll
    for (int it = 0; it < 2; ++it) {
      const int slot = it * 256 + tid;   // 0..511
      const int row = slot >> 3;         // 0..63
      const int g = slot & 7;
      const int gs = (g ^ (row & 7)) * 8;  // inverse-swizzled source granule
      async_copy16(Kh + (size_t)(k0 + row) * 64 + gs, &lds_k[bufi][slot * 8]);
      async_copy16(Vth + (size_t)row * 2048 + k0 + gs, &lds_vt[bufi][slot * 8]);
    }
    if (tid < 64) lds_biasf[bufi][tid] = pad[b * S + k0 + tid] ? 0.f : NEG;
    const int pvn = pad[b * S + k0 + lane];   // per-wave ballot source
    if (bufi) pv1 = pvn; else pv0 = pvn;
  };

  const int kend = q0 + 64;  // last k-tile origin (inclusive)
  stage(0, 0);
  __syncthreads();  // drains vmcnt(0): tile 0 resident
  int cur = 0;

  for (int k0 = 0; k0 <= kend; k0 += 64) {
    if (k0 < kend) stage(k0 + 64, cur ^ 1);  // prefetch next tile

    if (k0 <= qb + 31) {  // wave-uniform: skip fully-masked tiles
      const u16* lk = lds_k[cur];
      const u16* lvt = lds_vt[cur];
      const float* lb = lds_biasf[cur];
      const int pvc = cur ? pv1 : pv0;
      const bool fast = (__ballot(pvc != 0) == ~0ull);
      const bool needMask = (k0 + 63 > qb);
      const int thrh = qb + l31 - k0 - 4 * hi;  // mask iff rm+32*kt > thrh

      // ---- QK^T swapped: S[kpos][q], kpos reg-mapped, q = l31 ----
      f32x16 sacc0, sacc1;
#pragma unroll
      for (int r = 0; r < 16; ++r) { sacc0[r] = 0.f; sacc1[r] = 0.f; }
#pragma unroll
      for (int c = 0; c < 4; ++c) {
        const int gsw = ((2 * c + hi) ^ l7) * 8;
        bf16x8 kf0 = *(const bf16x8*)(lk + l31 * 64 + gsw);
        bf16x8 kf1 = *(const bf16x8*)(lk + (l31 + 32) * 64 + gsw);
        sacc0 = MFMA32(kf0, qfrag[c], sacc0);
        sacc1 = MFMA32(kf1, qfrag[c], sacc1);
      }

      // ---- softmax in-register + pack to PV A-frags ----
      bf16x8 pa[2][2];
#pragma unroll
      for (int kt = 0; kt < 2; ++kt) {
        float pe[16];
        if (fast) {
#pragma unroll
          for (int r = 0; r < 16; ++r) {
            float s = (kt == 0) ? sacc0[r] : sacc1[r];
            if (needMask) {
              const int rm = (r & 3) + 8 * (r >> 2) + 32 * kt;
              s = (rm > thrh) ? NEG : s;
            }
            pe[r] = __builtin_amdgcn_exp2f(s);
          }
        } else {
          f32x4 bv[4];
#pragma unroll
          for (int g = 0; g < 4; ++g)
            bv[g] = *(const f32x4*)(lb + g * 8 + 4 * hi + 32 * kt);
#pragma unroll
          for (int r = 0; r < 16; ++r) {
            float s = ((kt == 0) ? sacc0[r] : sacc1[r]) + bv[r >> 2][r & 3];
            if (needMask) {
              const int rm = (r & 3) + 8 * (r >> 2) + 32 * kt;
              s = (rm > thrh) ? NEG : s;
            }
            pe[r] = __builtin_amdgcn_exp2f(s);
          }
        }
        u32 a0 = cvt_pk_bf16(pe[0], pe[1]), a1 = cvt_pk_bf16(pe[2], pe[3]);
        u32 b0 = cvt_pk_bf16(pe[4], pe[5]), b1 = cvt_pk_bf16(pe[6], pe[7]);
        swap32(a0, b0);
        swap32(a1, b1);
        u32x4 w0 = {a0, a1, b0, b1};
        pa[kt][0] = __builtin_bit_cast(bf16x8, w0);
        u32 c0 = cvt_pk_bf16(pe[8], pe[9]), c1 = cvt_pk_bf16(pe[10], pe[11]);
        u32 d0 = cvt_pk_bf16(pe[12], pe[13]), d1 = cvt_pk_bf16(pe[14], pe[15]);
        swap32(c0, d0);
        swap32(c1, d1);
        u32x4 w1 = {c0, c1, d0, d1};
        pa[kt][1] = __builtin_bit_cast(bf16x8, w1);
      }

      // ---- PV + row-sum: O[q][d] and l[q], q reg-mapped ----
      __builtin_amdgcn_s_setprio(1);
#pragma unroll
      for (int kt = 0; kt < 2; ++kt)
#pragma unroll
        for (int ks = 0; ks < 2; ++ks) {
          const int kq = kt * 2 + ks;
          lacc = MFMA32(pa[kt][ks], ones, lacc);
          const int gsw = ((2 * kq + hi) ^ l7) * 8;
          bf16x8 vf0 = *(const bf16x8*)(lvt + l31 * 64 + gsw);
          bf16x8 vf1 = *(const bf16x8*)(lvt + (l31 + 32) * 64 + gsw);
          o_acc0 = MFMA32(pa[kt][ks], vf0, o_acc0);
          o_acc1 = MFMA32(pa[kt][ks], vf1, o_acc1);
        }
      __builtin_amdgcn_s_setprio(0);
    }

    __syncthreads();  // drains vmcnt(0) (prefetch landed) + all reads of cur done
    cur ^= 1;
  }

  // epilogue: normalize, write [B][S][H*64]
#pragma unroll
  for (int r = 0; r < 16; ++r) {
    const int q = qb + (r & 3) + 8 * (r >> 2) + 4 * hi;
    const float l = lacc[r];
    const float rl = (l > 0.f) ? (1.0f / l) : 0.f;
    O[(size_t)(b * S + q) * 1024 + h * 64 + l31] = f2bf(o_acc0[r] * rl);
    O[(size_t)(b * S + q) * 1024 + h * 64 + 32 + l31] = f2bf(o_acc1[r] * rl);
  }
}

// ---------- kernel 3: output projection (writes fp32 to d_out) ----------

__global__ __launch_bounds__(512, 2) void oproj_kernel(
    const u16* __restrict__ A, const u16* __restrict__ w_o, float* __restrict__ out) {
  __shared__ u16 lds[49152];
  f32x4 acc[4][4];
  const int row0 = blockIdx.y * 256;
  const int col0 = blockIdx.x * 128;
  gemm256_bt(A, w_o, row0, col0, lds, acc);
  const int tid = threadIdx.x;
  const int wave = tid >> 6, lane = tid & 63;
  const int fr = lane & 15, quad = lane >> 4;
  const int wm = (wave >> 1) * 64, wn = (wave & 1) * 64;
#pragma unroll
  for (int mt = 0; mt < 4; ++mt)
#pragma unroll
    for (int nt = 0; nt < 4; ++nt) {
      const int ncol = col0 + wn + nt * 16 + fr;
#pragma unroll
      for (int r = 0; r < 4; ++r) {
        const int mrow = row0 + wm + mt * 16 + quad * 4 + r;
        out[(size_t)mrow * 1024 + ncol] = acc[mt][nt][r];
      }
    }
}

// ---------- launch ----------

extern "C" void kernel_launch(void* const* d_in, const int* in_sizes, int n_in,
                              void* d_out, int out_size, void* d_ws, size_t ws_size,
                              hipStream_t stream) {
  const float* x_f = (const float*)d_in[0];     // [4][2048][1024] fp32
  const int* pad = (const int*)d_in[1];         // [4][2048] int32
  const float* wqkv_f = (const float*)d_in[2];  // [3072][1024] fp32
  const float* wo_f = (const float*)d_in[3];    // [1024][1024] fp32
  float* out = (float*)d_out;                   // [4][2048][1024] fp32

  const int NX = 4 * 2048 * 1024;
  const int NWQKV = 3072 * 1024;
  const int NWO = 1024 * 1024;
  const size_t HSZ = (size_t)4 * 16 * 2048 * 64;  // 8M elems per head-tensor

  u16* xb = (u16*)d_ws;            // 16 MB
  u16* wqkvb = xb + NX;            // 6 MB
  u16* wob = wqkvb + NWQKV;        // 2 MB
  u16* q_ws = wob + NWO;           // 16 MB  [B][H][S][64] (pre-scaled, roped)
  u16* k_ws = q_ws + HSZ;          // 16 MB  [B][H][S][64] (roped)
  u16* vt_ws = k_ws + HSZ;         // 16 MB  [B][H][64][S] (transposed)
  u16* attn_ws = vt_ws + HSZ;      // 16 MB  [B*S][D]
  float2* rope_t = (float2*)(attn_ws + HSZ);  // 512 KB [2048][32]

  prep_kernel<<<dim3(12544), dim3(256), 0, stream>>>(x_f, wqkv_f, wo_f, xb, wqkvb,
                                                     wob, rope_t);
  qkv_rope_kernel<<<dim3(12, 32), dim3(512), 0, stream>>>(xb, wqkvb, rope_t, q_ws,
                                                          k_ws, vt_ws);
  flash_attn_kernel<<<dim3(1024), dim3(256), 0, stream>>>(q_ws, k_ws, vt_ws, pad,
                                                          attn_ws);
  oproj_kernel<<<dim3(8, 32), dim3(512), 0, stream>>>(attn_ws, wob, out);
}

// Round 7
// 262.026 us; speedup vs baseline: 1.0110x; 1.0110x over previous
//
#include <hip/hip_runtime.h>

typedef unsigned short u16;
typedef unsigned int u32;
typedef __bf16 bf16x8 __attribute__((ext_vector_type(8)));
typedef float f32x4 __attribute__((ext_vector_type(4)));
typedef float f32x16 __attribute__((ext_vector_type(16)));
typedef u32 u32x4 __attribute__((ext_vector_type(4)));

#define MFMA_BF16(a, b, c) __builtin_amdgcn_mfma_f32_16x16x32_bf16((a), (b), (c), 0, 0, 0)
#define MFMA32(a, b, c) __builtin_amdgcn_mfma_f32_32x32x16_bf16((a), (b), (c), 0, 0, 0)

// log2-domain constant: 0.125 * log2(e), folded into w_qkv Q-rows at prep
#define QSCALE 0.18033688011112042f

#define BARRIER __builtin_amdgcn_s_barrier()
#define LGKM0                                                \
  do {                                                       \
    asm volatile("s_waitcnt lgkmcnt(0)" ::: "memory");       \
    __builtin_amdgcn_sched_barrier(0);                       \
  } while (0)
#define WAIT_VM(N) asm volatile("s_waitcnt vmcnt(" #N ")" ::: "memory")

// ---------- helpers ----------

__device__ __forceinline__ u16 f2bf(float f) {
  u32 u = __builtin_bit_cast(u32, f);
  u += 0x7fffu + ((u >> 16) & 1u);   // RNE
  return (u16)(u >> 16);
}

__device__ __forceinline__ void async_copy16(const void* g, void* l) {
  __builtin_amdgcn_global_load_lds(
      (__attribute__((address_space(1))) void*)g,
      (__attribute__((address_space(3))) void*)l, 16, 0, 0);
}

__device__ __forceinline__ u32 cvt_pk_bf16(float lo, float hi) {
  u32 d;
  asm("v_cvt_pk_bf16_f32 %0, %1, %2" : "=v"(d) : "v"(lo), "v"(hi));
  return d;
}

__device__ __forceinline__ void swap32(u32& a, u32& b) {
  asm("v_permlane32_swap_b32 %0, %1" : "+v"(a), "+v"(b));
}

// ---------- kernel 0: fused fp32->bf16 converts + RoPE cos/sin table ----------

__global__ __launch_bounds__(256) void prep_kernel(
    const float* __restrict__ x_f, const float* __restrict__ wqkv_f,
    const float* __restrict__ wo_f, u16* __restrict__ xb,
    u16* __restrict__ wqkvb, u16* __restrict__ wob, float2* __restrict__ rope_t) {
  const int blk = blockIdx.x;
  if (blk < 12288) {
    const float* src;
    u16* dst;
    int base;
    float scale = 1.0f;
    if (blk < 8192)      { src = x_f;    dst = xb;    base = blk; }
    else if (blk < 11264){ src = wqkv_f; dst = wqkvb; base = blk - 8192;
                           if (base < 1024) scale = QSCALE; }  // Q rows
    else                 { src = wo_f;   dst = wob;   base = blk - 11264; }
    const int i = base * 1024 + threadIdx.x * 4;
    const float4 v = *(const float4*)(src + i);
    ushort4 o;
    o.x = f2bf(v.x * scale); o.y = f2bf(v.y * scale);
    o.z = f2bf(v.z * scale); o.w = f2bf(v.w * scale);
    *(ushort4*)(dst + i) = o;
  } else {
    const int idx = (blk - 12288) * 256 + threadIdx.x;  // [0, 65536)
    const int s = idx >> 5, i = idx & 31;
    const float invf = __builtin_amdgcn_exp2f(-(float)i * 0.41524101186092027f);
    float rev = (float)s * invf * 0.15915494309189535f;  // radians -> revolutions
    rev -= floorf(rev);
    rope_t[idx] = make_float2(__builtin_amdgcn_cosf(rev), __builtin_amdgcn_sinf(rev));
  }
}

// ---------- 256x256 GEMM-BT core, fine-interleaved 8-phase (m201/m196) -------
// 512 thr = 8 waves (2M x 4N); per-wave 128x64 = acc[8][4]; BK=64 as 2 K-halves.
// LDS per dbuf: [Akk0 256x32][Bkk0][Akk1][Bkk1] = 64 KB; 2 dbuf = 128 KB.
// Per K-tile: 4 phases {4-8 ds_read_b128 || stage ONE 16KB K-half (2 gload_lds)
//   -> barrier -> lgkmcnt(0) -> setprio(1)+16 MFMA+setprio(0) -> barrier},
// counted vmcnt(4) at end of phases 2 and 4 (never 0 mid-loop).
// Steady state: 8 loads in flight; each half-tile ~4 phases of latency cover.
// Swizzle: granule g ^= (row>>1)&3 (involution on gload source + ds_read addr);
// 16-lane fr read spread over (fr&1, g) -> 2 lanes/bank slot = conflict-free.
// Stage targets verified write-after-read safe vs the barrier chain:
//   P1 -> obuf.Akk1 (last read P4(t-1)); P2 -> obuf.Bkk1 (P3(t-1));
//   P3 -> cbuf.Akk0 (P2(t));            P4 -> cbuf.Bkk0 (P1(t)).

__device__ __forceinline__ void gemm256x8(const u16* __restrict__ A,
                                          const u16* __restrict__ B,
                                          int row0, int col0, u16* lds,
                                          f32x4 acc[8][4]) {
  const int tid = threadIdx.x;
  const int wave = tid >> 6, lane = tid & 63;
  const int fr = lane & 15, quad = lane >> 4;
  const int wr = wave >> 2, wc = wave & 3;
  const int wm = wr * 128, wn = wc * 64;

  f32x4 zero = {0.f, 0.f, 0.f, 0.f};
#pragma unroll
  for (int mt = 0; mt < 8; ++mt)
#pragma unroll
    for (int nt = 0; nt < 4; ++nt) acc[mt][nt] = zero;

  // stage one K-half of one operand: 256 rows x 32 cols = 16 KB, 2 insts/thread
  auto stageH = [&](const u16* src, int baserow, int kcol, u16* dst) {
#pragma unroll
    for (int it = 0; it < 2; ++it) {
      const int slot = it * 512 + tid;        // 0..1023
      const int row = slot >> 2, g = slot & 3;
      const int glog = g ^ ((row >> 1) & 3);  // inverse-swizzled source granule
      async_copy16(src + (size_t)(baserow + row) * 1024 + kcol + glog * 8,
                   dst + slot * 8);
    }
  };

  // per-thread fragment offset within a [256][32] half-tile (swizzled read)
  const int rbase = fr * 32 + (quad ^ ((fr >> 1) & 3)) * 8;

  u16* const d0 = lds;           // dbuf 0 (tiles with t&1 == 0)
  u16* const d1 = lds + 32768;   // dbuf 1

  // prologue: tile0 all 4 halves + tile1 kk0 halves (12 loads)
  stageH(A, row0, 0, d0);
  stageH(B, col0, 0, d0 + 8192);
  stageH(A, row0, 32, d0 + 16384);
  stageH(B, col0, 32, d0 + 24576);
  stageH(A, row0, 64, d1);
  stageH(B, col0, 64, d1 + 8192);
  WAIT_VM(4);   // tile0's 4 halves landed; Ak0(1),Bk0(1) in flight
  BARRIER;

  for (int t = 0; t < 16; ++t) {
    u16* const cb = (t & 1) ? d1 : d0;   // current tile buffer
    u16* const ob = (t & 1) ? d0 : d1;   // other buffer (tile t+1)
    const int k0 = t * 64;

    bf16x8 a[8], b[4];

    // ---- phase 1: read A kk0 m0-3 + B kk0 n0-3; stage Ak1(t+1) ----
#pragma unroll
    for (int m = 0; m < 4; ++m)
      a[m] = *(const bf16x8*)(cb + (wm + m * 16) * 32 + rbase);
#pragma unroll
    for (int n = 0; n < 4; ++n)
      b[n] = *(const bf16x8*)(cb + 8192 + (wn + n * 16) * 32 + rbase);
    if (t + 1 < 16) stageH(A, row0, k0 + 96, ob + 16384);
    BARRIER;
    LGKM0;
    __builtin_amdgcn_s_setprio(1);
#pragma unroll
    for (int m = 0; m < 4; ++m)
#pragma unroll
      for (int n = 0; n < 4; ++n)
        acc[m][n] = MFMA_BF16(a[m], b[n], acc[m][n]);
    __builtin_amdgcn_s_setprio(0);
    BARRIER;

    // ---- phase 2: read A kk0 m4-7; stage Bk1(t+1) ----
#pragma unroll
    for (int m = 0; m < 4; ++m)
      a[4 + m] = *(const bf16x8*)(cb + (wm + 64 + m * 16) * 32 + rbase);
    if (t + 1 < 16) stageH(B, col0, k0 + 96, ob + 24576);
    BARRIER;
    LGKM0;
    __builtin_amdgcn_s_setprio(1);
#pragma unroll
    for (int m = 0; m < 4; ++m)
#pragma unroll
      for (int n = 0; n < 4; ++n)
        acc[4 + m][n] = MFMA_BF16(a[4 + m], b[n], acc[4 + m][n]);
    __builtin_amdgcn_s_setprio(0);
    if (t < 15) { WAIT_VM(4); } else { WAIT_VM(0); }  // forces Ak1(t),Bk1(t)... landed
    BARRIER;

    // ---- phase 3: read A kk1 m0-3 + B kk1 n0-3; stage Ak0(t+2) ----
#pragma unroll
    for (int m = 0; m < 4; ++m)
      a[m] = *(const bf16x8*)(cb + 16384 + (wm + m * 16) * 32 + rbase);
#pragma unroll
    for (int n = 0; n < 4; ++n)
      b[n] = *(const bf16x8*)(cb + 24576 + (wn + n * 16) * 32 + rbase);
    if (t + 2 < 16) stageH(A, row0, k0 + 128, cb);
    BARRIER;
    LGKM0;
    __builtin_amdgcn_s_setprio(1);
#pragma unroll
    for (int m = 0; m < 4; ++m)
#pragma unroll
      for (int n = 0; n < 4; ++n)
        acc[m][n] = MFMA_BF16(a[m], b[n], acc[m][n]);
    __builtin_amdgcn_s_setprio(0);
    BARRIER;

    // ---- phase 4: read A kk1 m4-7; stage Bk0(t+2) ----
#pragma unroll
    for (int m = 0; m < 4; ++m)
      a[4 + m] = *(const bf16x8*)(cb + 16384 + (wm + 64 + m * 16) * 32 + rbase);
    if (t + 2 < 16) stageH(B, col0, k0 + 128, cb + 8192);
    BARRIER;
    LGKM0;
    __builtin_amdgcn_s_setprio(1);
#pragma unroll
    for (int m = 0; m < 4; ++m)
#pragma unroll
      for (int n = 0; n < 4; ++n)
        acc[4 + m][n] = MFMA_BF16(a[4 + m], b[n], acc[4 + m][n]);
    __builtin_amdgcn_s_setprio(0);
    if (t < 14) { WAIT_VM(4); } else { WAIT_VM(0); }  // forces next tile kk0 landed
    BARRIER;
  }
}

// ---------- kernel 1: QKV projection + RoPE, 2-pass coalesced epilogue -------
// 256x256 tiles: grid (12, 32) = 384 blocks (1 block/CU, 128 KB LDS).

__global__ __launch_bounds__(512, 2) void qkv_rope_kernel(
    const u16* __restrict__ x, const u16* __restrict__ w_qkv,
    const float2* __restrict__ rope_t,
    u16* __restrict__ q_ws, u16* __restrict__ k_ws, u16* __restrict__ vt_ws) {
  __shared__ u16 lds[65536];  // 128 KB: gemm dbuf; epilogue reuses it
  f32x4 acc[8][4];
  const int row0 = blockIdx.y * 256;  // M = 8192
  const int col0 = blockIdx.x * 256;  // N = 3072
  gemm256x8(x, w_qkv, row0, col0, lds, acc);

  const int tid = threadIdx.x;
  const int wave = tid >> 6, lane = tid & 63;
  const int fr = lane & 15, quad = lane >> 4;
  const int wr = wave >> 2, wc = wave & 3;
  const int wm = wr * 128;
  const int region = col0 >> 10;      // 0=Q 1=K 2=V (block-uniform; 1024%256==0)
  const int f0 = col0 & 1023;
  const int s0r = row0 & 2047;
  const int bb = row0 >> 11;
  const int h0 = f0 >> 6;             // block covers heads h0 .. h0+3

  // two 128-col passes so the stage buffer fits in 128 KB LDS
#pragma unroll
  for (int hp = 0; hp < 2; ++hp) {
    __syncthreads();
    if ((wc >> 1) == hp) {
      const int n1b = (wc & 1) * 64;
      if (region < 2) {
        // rotate in registers, stage [m 256][n1 128] (stride 136)
#pragma unroll
        for (int mt = 0; mt < 8; ++mt)
#pragma unroll
          for (int nt = 0; nt < 4; ++nt) {
            const int n1 = n1b + nt * 16 + fr;
            const int d = n1 & 63;
#pragma unroll
            for (int r = 0; r < 4; ++r) {
              const int m = wm + mt * 16 + quad * 4 + r;
              const float own = acc[mt][nt][r];
              const float part = __shfl_xor(own, 1);
              const float2 cssn = rope_t[(s0r + m) * 32 + (d >> 1)];
              const float val = (d & 1) ? (part * cssn.y + own * cssn.x)
                                        : (own * cssn.x - part * cssn.y);
              lds[m * 136 + n1] = f2bf(val);
            }
          }
      } else {
        // stage transposed [n1 128][m 256] (stride 264)
#pragma unroll
        for (int mt = 0; mt < 8; ++mt)
#pragma unroll
          for (int nt = 0; nt < 4; ++nt) {
            const int n1 = n1b + nt * 16 + fr;
#pragma unroll
            for (int r = 0; r < 4; ++r) {
              const int m = wm + mt * 16 + quad * 4 + r;
              lds[n1 * 264 + m] = f2bf(acc[mt][nt][r]);
            }
          }
      }
    }
    __syncthreads();
    if (region < 2) {
      u16* dst = (region == 0) ? q_ws : k_ws;
#pragma unroll
      for (int j = 0; j < 8; ++j) {
        const int idx2 = j * 512 + tid;       // 0..4095
        const int m = idx2 >> 4;              // 0..255
        const int rem = idx2 & 15;
        const int hf = rem >> 3;              // head half within pass
        const int c8 = (rem & 7) * 8;
        const uint4 v = *(const uint4*)(lds + m * 136 + hf * 64 + c8);
        *(uint4*)(dst + ((size_t)(bb * 16 + h0 + hp * 2 + hf) * 2048 + s0r + m) * 64 +
                  c8) = v;
      }
    } else {
#pragma unroll
      for (int j = 0; j < 8; ++j) {
        const int idx2 = j * 512 + tid;       // 0..4095
        const int n1 = idx2 >> 5;             // 0..127
        const int mc = (idx2 & 31) * 8;       // 0..248
        const int ng = hp * 128 + n1;
        const int h = h0 + (ng >> 6);
        const int d = ng & 63;
        const uint4 v = *(const uint4*)(lds + n1 * 264 + mc);
        *(uint4*)(vt_ws + ((size_t)(bb * 16 + h) * 64 + d) * 2048 + s0r + mc) = v;
      }
    }
  }
}

// ---------- 256x128 GEMM-BT core (r2 structure) — used by oproj ----------

__device__ __forceinline__ void gemm256_bt(const u16* __restrict__ A,
                                           const u16* __restrict__ B,
                                           int row0, int col0, u16* lds,
                                           f32x4 acc[4][4]) {
  const int tid = threadIdx.x;
  const int wave = tid >> 6, lane = tid & 63;
  const int fr = lane & 15, quad = lane >> 4;
  const int wm = (wave >> 1) * 64;   // 0,64,128,192
  const int wn = (wave & 1) * 64;    // 0,64
  u16* bufA0 = lds;                  // [256][64]
  u16* bufB0 = lds + 16384;          // [128][64]
  u16* bufA1 = lds + 24576;
  u16* bufB1 = lds + 40960;

  const int l8 = lane >> 3, l7 = lane & 7;
  const int csw = (l7 ^ l8) * 8;     // pre-swizzled source col (l8 < 8)

  f32x4 zero = {0.f, 0.f, 0.f, 0.f};
#pragma unroll
  for (int mt = 0; mt < 4; ++mt)
#pragma unroll
    for (int nt = 0; nt < 4; ++nt) acc[mt][nt] = zero;

  auto stage = [&](int t) {
    u16* ba = (t & 1) ? bufA1 : bufA0;
    u16* bb = (t & 1) ? bufB1 : bufB0;
    const int k0 = t * 64;
#pragma unroll
    for (int c = 0; c < 4; ++c) {
      const int ch = c * 8 + wave;   // 0..31 -> rows [ch*8, ch*8+8)
      async_copy16(A + (size_t)(row0 + ch * 8 + l8) * 1024 + k0 + csw,
                   ba + ch * 512);
    }
#pragma unroll
    for (int c = 0; c < 2; ++c) {
      const int ch = c * 8 + wave;   // 0..15
      async_copy16(B + (size_t)(col0 + ch * 8 + l8) * 1024 + k0 + csw,
                   bb + ch * 512);
    }
  };

  const int f7 = fr & 7;
  const int sw0 = (quad ^ f7) * 8;         // kk = 0
  const int sw1 = ((quad + 4) ^ f7) * 8;   // kk = 1
  const int ar0 = (wm + fr) * 64, ar1 = (wm + 16 + fr) * 64;
  const int ar2 = (wm + 32 + fr) * 64, ar3 = (wm + 48 + fr) * 64;
  const int br0 = (wn + fr) * 64, br1 = (wn + 16 + fr) * 64;
  const int br2 = (wn + 32 + fr) * 64, br3 = (wn + 48 + fr) * 64;

  stage(0);
  stage(1);
  WAIT_VM(6);
  BARRIER;

  for (int t = 0; t < 16; ++t) {
    const u16* ba = (t & 1) ? bufA1 : bufA0;
    const u16* bb = (t & 1) ? bufB1 : bufB0;

    bf16x8 a0k0 = *(const bf16x8*)(ba + ar0 + sw0);
    bf16x8 a0k1 = *(const bf16x8*)(ba + ar0 + sw1);
    bf16x8 a1k0 = *(const bf16x8*)(ba + ar1 + sw0);
    bf16x8 a1k1 = *(const bf16x8*)(ba + ar1 + sw1);
    bf16x8 b0k0 = *(const bf16x8*)(bb + br0 + sw0);
    bf16x8 b0k1 = *(const bf16x8*)(bb + br0 + sw1);
    bf16x8 b1k0 = *(const bf16x8*)(bb + br1 + sw0);
    bf16x8 b1k1 = *(const bf16x8*)(bb + br1 + sw1);
    BARRIER;
    LGKM0;
    __builtin_amdgcn_s_setprio(1);
    acc[0][0] = MFMA_BF16(a0k0, b0k0, acc[0][0]);
    acc[0][1] = MFMA_BF16(a0k0, b1k0, acc[0][1]);
    acc[1][0] = MFMA_BF16(a1k0, b0k0, acc[1][0]);
    acc[1][1] = MFMA_BF16(a1k0, b1k0, acc[1][1]);
    acc[0][0] = MFMA_BF16(a0k1, b0k1, acc[0][0]);
    acc[0][1] = MFMA_BF16(a0k1, b1k1, acc[0][1]);
    acc[1][0] = MFMA_BF16(a1k1, b0k1, acc[1][0]);
    acc[1][1] = MFMA_BF16(a1k1, b1k1, acc[1][1]);
    __builtin_amdgcn_s_setprio(0);
    BARRIER;

    bf16x8 b2k0 = *(const bf16x8*)(bb + br2 + sw0);
    bf16x8 b2k1 = *(const bf16x8*)(bb + br2 + sw1);
    bf16x8 b3k0 = *(const bf16x8*)(bb + br3 + sw0);
    bf16x8 b3k1 = *(const bf16x8*)(bb + br3 + sw1);
    BARRIER;
    LGKM0;
    __builtin_amdgcn_s_setprio(1);
    acc[0][2] = MFMA_BF16(a0k0, b2k0, acc[0][2]);
    acc[0][3] = MFMA_BF16(a0k0, b3k0, acc[0][3]);
    acc[1][2] = MFMA_BF16(a1k0, b2k0, acc[1][2]);
    acc[1][3] = MFMA_BF16(a1k0, b3k0, acc[1][3]);
    acc[0][2] = MFMA_BF16(a0k1, b2k1, acc[0][2]);
    acc[0][3] = MFMA_BF16(a0k1, b3k1, acc[0][3]);
    acc[1][2] = MFMA_BF16(a1k1, b2k1, acc[1][2]);
    acc[1][3] = MFMA_BF16(a1k1, b3k1, acc[1][3]);
    __builtin_amdgcn_s_setprio(0);
    BARRIER;

    bf16x8 a2k0 = *(const bf16x8*)(ba + ar2 + sw0);
    bf16x8 a2k1 = *(const bf16x8*)(ba + ar2 + sw1);
    bf16x8 a3k0 = *(const bf16x8*)(ba + ar3 + sw0);
    bf16x8 a3k1 = *(const bf16x8*)(ba + ar3 + sw1);
    BARRIER;
    LGKM0;
    __builtin_amdgcn_s_setprio(1);
    acc[2][0] = MFMA_BF16(a2k0, b0k0, acc[2][0]);
    acc[2][1] = MFMA_BF16(a2k0, b1k0, acc[2][1]);
    acc[3][0] = MFMA_BF16(a3k0, b0k0, acc[3][0]);
    acc[3][1] = MFMA_BF16(a3k0, b1k0, acc[3][1]);
    acc[2][0] = MFMA_BF16(a2k1, b0k1, acc[2][0]);
    acc[2][1] = MFMA_BF16(a2k1, b1k1, acc[2][1]);
    acc[3][0] = MFMA_BF16(a3k1, b0k1, acc[3][0]);
    acc[3][1] = MFMA_BF16(a3k1, b1k1, acc[3][1]);
    acc[2][2] = MFMA_BF16(a2k0, b2k0, acc[2][2]);
    acc[2][3] = MFMA_BF16(a2k0, b3k0, acc[2][3]);
    acc[3][2] = MFMA_BF16(a3k0, b2k0, acc[3][2]);
    acc[3][3] = MFMA_BF16(a3k0, b3k0, acc[3][3]);
    acc[2][2] = MFMA_BF16(a2k1, b2k1, acc[2][2]);
    acc[2][3] = MFMA_BF16(a2k1, b3k1, acc[2][3]);
    acc[3][2] = MFMA_BF16(a3k1, b2k1, acc[3][2]);
    acc[3][3] = MFMA_BF16(a3k1, b3k1, acc[3][3]);
    __builtin_amdgcn_s_setprio(0);

    BARRIER;
    if (t + 2 < 16) {
      stage(t + 2);
      WAIT_VM(6);
    } else if (t + 2 == 16) {
      WAIT_VM(0);
    }
    BARRIER;
  }
}

// ---------- kernel 2: causal flash attention, swapped-QK 32x32 in-reg softmax -
// (verified r3 structure, unchanged)

__global__ __launch_bounds__(256, 3) void flash_attn_kernel(
    const u16* __restrict__ Q, const u16* __restrict__ K, const u16* __restrict__ Vt,
    const int* __restrict__ pad, u16* __restrict__ O) {
  const int S = 2048;
  const int idx = blockIdx.x;
  const int bh = idx & 63;
  const int b = bh >> 4, h = bh & 15;
  // balanced q-tile remap: perm = [[0,1,2,3],[7,6,5,4],[8,9,10,11],[15,14,13,12]]
  const int j = (idx >> 6) & 3;
  const int sr = idx >> 8;
  const int qt_rev = (sr >> 1) * 8 + ((sr & 1) ? (7 - j) : j);
  const int q0 = (15 - qt_rev) * 128;
  const u16* Qh = Q + (size_t)bh * S * 64;
  const u16* Kh = K + (size_t)bh * S * 64;
  const u16* Vth = Vt + (size_t)bh * 64 * S;
  const int tid = threadIdx.x, wave = tid >> 6, lane = tid & 63;
  const int l31 = lane & 31, hi = lane >> 5, l7 = lane & 7;

  __shared__ u16 lds_k[2][64 * 64];    // dbuf [kpos 64][d 64] swizzled  16 KB
  __shared__ u16 lds_vt[2][64 * 64];   // dbuf [d 64][kpos 64] swizzled  16 KB
  __shared__ float lds_biasf[2][64];   // {0, -inf} per kpos             512 B

  const int qb = q0 + wave * 32;  // wave's first q row

  // Q as B-operand: lane holds Q[qb + l31][d = c*16 + hi*8 + 0..7]
  bf16x8 qfrag[4];
#pragma unroll
  for (int c = 0; c < 4; ++c)
    qfrag[c] = *(const bf16x8*)(Qh + (size_t)(qb + l31) * 64 + c * 16 + hi * 8);

  bf16x8 ones;
#pragma unroll
  for (int jj = 0; jj < 8; ++jj) ones[jj] = (__bf16)1.0f;

  f32x16 o_acc0, o_acc1, lacc;
#pragma unroll
  for (int r = 0; r < 16; ++r) { o_acc0[r] = 0.f; o_acc1[r] = 0.f; lacc[r] = 0.f; }

  const float NEG = -__builtin_inff();
  int pv0 = 1, pv1 = 1;

  auto stage = [&](int k0, int bufi) {
#pragma unroll
    for (int it = 0; it < 2; ++it) {
      const int slot = it * 256 + tid;   // 0..511
      const int row = slot >> 3;         // 0..63
      const int g = slot & 7;
      const int gs = (g ^ (row & 7)) * 8;  // inverse-swizzled source granule
      async_copy16(Kh + (size_t)(k0 + row) * 64 + gs, &lds_k[bufi][slot * 8]);
      async_copy16(Vth + (size_t)row * 2048 + k0 + gs, &lds_vt[bufi][slot * 8]);
    }
    if (tid < 64) lds_biasf[bufi][tid] = pad[b * S + k0 + tid] ? 0.f : NEG;
    const int pvn = pad[b * S + k0 + lane];   // per-wave ballot source
    if (bufi) pv1 = pvn; else pv0 = pvn;
  };

  const int kend = q0 + 64;  // last k-tile origin (inclusive)
  stage(0, 0);
  __syncthreads();  // drains vmcnt(0): tile 0 resident
  int cur = 0;

  for (int k0 = 0; k0 <= kend; k0 += 64) {
    if (k0 < kend) stage(k0 + 64, cur ^ 1);  // prefetch next tile

    if (k0 <= qb + 31) {  // wave-uniform: skip fully-masked tiles
      const u16* lk = lds_k[cur];
      const u16* lvt = lds_vt[cur];
      const float* lb = lds_biasf[cur];
      const int pvc = cur ? pv1 : pv0;
      const bool fast = (__ballot(pvc != 0) == ~0ull);
      const bool needMask = (k0 + 63 > qb);
      const int thrh = qb + l31 - k0 - 4 * hi;  // mask iff rm+32*kt > thrh

      // ---- QK^T swapped: S[kpos][q], kpos reg-mapped, q = l31 ----
      f32x16 sacc0, sacc1;
#pragma unroll
      for (int r = 0; r < 16; ++r) { sacc0[r] = 0.f; sacc1[r] = 0.f; }
#pragma unroll
      for (int c = 0; c < 4; ++c) {
        const int gsw = ((2 * c + hi) ^ l7) * 8;
        bf16x8 kf0 = *(const bf16x8*)(lk + l31 * 64 + gsw);
        bf16x8 kf1 = *(const bf16x8*)(lk + (l31 + 32) * 64 + gsw);
        sacc0 = MFMA32(kf0, qfrag[c], sacc0);
        sacc1 = MFMA32(kf1, qfrag[c], sacc1);
      }

      // ---- softmax in-register + pack to PV A-frags ----
      bf16x8 pa[2][2];
#pragma unroll
      for (int kt = 0; kt < 2; ++kt) {
        float pe[16];
        if (fast) {
#pragma unroll
          for (int r = 0; r < 16; ++r) {
            float s = (kt == 0) ? sacc0[r] : sacc1[r];
            if (needMask) {
              const int rm = (r & 3) + 8 * (r >> 2) + 32 * kt;
              s = (rm > thrh) ? NEG : s;
            }
            pe[r] = __builtin_amdgcn_exp2f(s);
          }
        } else {
          f32x4 bv[4];
#pragma unroll
          for (int g = 0; g < 4; ++g)
            bv[g] = *(const f32x4*)(lb + g * 8 + 4 * hi + 32 * kt);
#pragma unroll
          for (int r = 0; r < 16; ++r) {
            float s = ((kt == 0) ? sacc0[r] : sacc1[r]) + bv[r >> 2][r & 3];
            if (needMask) {
              const int rm = (r & 3) + 8 * (r >> 2) + 32 * kt;
              s = (rm > thrh) ? NEG : s;
            }
            pe[r] = __builtin_amdgcn_exp2f(s);
          }
        }
        u32 a0 = cvt_pk_bf16(pe[0], pe[1]), a1 = cvt_pk_bf16(pe[2], pe[3]);
        u32 b0 = cvt_pk_bf16(pe[4], pe[5]), b1 = cvt_pk_bf16(pe[6], pe[7]);
        swap32(a0, b0);
        swap32(a1, b1);
        u32x4 w0 = {a0, a1, b0, b1};
        pa[kt][0] = __builtin_bit_cast(bf16x8, w0);
        u32 c0 = cvt_pk_bf16(pe[8], pe[9]), c1 = cvt_pk_bf16(pe[10], pe[11]);
        u32 d0 = cvt_pk_bf16(pe[12], pe[13]), d1 = cvt_pk_bf16(pe[14], pe[15]);
        swap32(c0, d0);
        swap32(c1, d1);
        u32x4 w1 = {c0, c1, d0, d1};
        pa[kt][1] = __builtin_bit_cast(bf16x8, w1);
      }

      // ---- PV + row-sum: O[q][d] and l[q], q reg-mapped ----
      __builtin_amdgcn_s_setprio(1);
#pragma unroll
      for (int kt = 0; kt < 2; ++kt)
#pragma unroll
        for (int ks = 0; ks < 2; ++ks) {
          const int kq = kt * 2 + ks;
          lacc = MFMA32(pa[kt][ks], ones, lacc);
          const int gsw = ((2 * kq + hi) ^ l7) * 8;
          bf16x8 vf0 = *(const bf16x8*)(lvt + l31 * 64 + gsw);
          bf16x8 vf1 = *(const bf16x8*)(lvt + (l31 + 32) * 64 + gsw);
          o_acc0 = MFMA32(pa[kt][ks], vf0, o_acc0);
          o_acc1 = MFMA32(pa[kt][ks], vf1, o_acc1);
        }
      __builtin_amdgcn_s_setprio(0);
    }

    __syncthreads();  // drains vmcnt(0) (prefetch landed) + all reads of cur done
    cur ^= 1;
  }

  // epilogue: normalize, write [B][S][H*64]
#pragma unroll
  for (int r = 0; r < 16; ++r) {
    const int q = qb + (r & 3) + 8 * (r >> 2) + 4 * hi;
    const float l = lacc[r];
    const float rl = (l > 0.f) ? (1.0f / l) : 0.f;
    O[(size_t)(b * S + q) * 1024 + h * 64 + l31] = f2bf(o_acc0[r] * rl);
    O[(size_t)(b * S + q) * 1024 + h * 64 + 32 + l31] = f2bf(o_acc1[r] * rl);
  }
}

// ---------- kernel 3: output projection (writes fp32 to d_out) ----------

__global__ __launch_bounds__(512, 2) void oproj_kernel(
    const u16* __restrict__ A, const u16* __restrict__ w_o, float* __restrict__ out) {
  __shared__ u16 lds[49152];
  f32x4 acc[4][4];
  const int row0 = blockIdx.y * 256;
  const int col0 = blockIdx.x * 128;
  gemm256_bt(A, w_o, row0, col0, lds, acc);
  const int tid = threadIdx.x;
  const int wave = tid >> 6, lane = tid & 63;
  const int fr = lane & 15, quad = lane >> 4;
  const int wm = (wave >> 1) * 64, wn = (wave & 1) * 64;
#pragma unroll
  for (int mt = 0; mt < 4; ++mt)
#pragma unroll
    for (int nt = 0; nt < 4; ++nt) {
      const int ncol = col0 + wn + nt * 16 + fr;
#pragma unroll
      for (int r = 0; r < 4; ++r) {
        const int mrow = row0 + wm + mt * 16 + quad * 4 + r;
        out[(size_t)mrow * 1024 + ncol] = acc[mt][nt][r];
      }
    }
}

// ---------- launch ----------

extern "C" void kernel_launch(void* const* d_in, const int* in_sizes, int n_in,
                              void* d_out, int out_size, void* d_ws, size_t ws_size,
                              hipStream_t stream) {
  const float* x_f = (const float*)d_in[0];     // [4][2048][1024] fp32
  const int* pad = (const int*)d_in[1];         // [4][2048] int32
  const float* wqkv_f = (const float*)d_in[2];  // [3072][1024] fp32
  const float* wo_f = (const float*)d_in[3];    // [1024][1024] fp32
  float* out = (float*)d_out;                   // [4][2048][1024] fp32

  const int NX = 4 * 2048 * 1024;
  const int NWQKV = 3072 * 1024;
  const int NWO = 1024 * 1024;
  const size_t HSZ = (size_t)4 * 16 * 2048 * 64;  // 8M elems per head-tensor

  u16* xb = (u16*)d_ws;            // 16 MB
  u16* wqkvb = xb + NX;            // 6 MB
  u16* wob = wqkvb + NWQKV;        // 2 MB
  u16* q_ws = wob + NWO;           // 16 MB  [B][H][S][64] (pre-scaled, roped)
  u16* k_ws = q_ws + HSZ;          // 16 MB  [B][H][S][64] (roped)
  u16* vt_ws = k_ws + HSZ;         // 16 MB  [B][H][64][S] (transposed)
  u16* attn_ws = vt_ws + HSZ;      // 16 MB  [B*S][D]
  float2* rope_t = (float2*)(attn_ws + HSZ);  // 512 KB [2048][32]

  prep_kernel<<<dim3(12544), dim3(256), 0, stream>>>(x_f, wqkv_f, wo_f, xb, wqkvb,
                                                     wob, rope_t);
  qkv_rope_kernel<<<dim3(12, 32), dim3(512), 0, stream>>>(xb, wqkvb, rope_t, q_ws,
                                                          k_ws, vt_ws);
  flash_attn_kernel<<<dim3(1024), dim3(256), 0, stream>>>(q_ws, k_ws, vt_ws, pad,
                                                          attn_ws);
  oproj_kernel<<<dim3(8, 32), dim3(512), 0, stream>>>(attn_ws, wob, out);
}

// Round 8
// 253.230 us; speedup vs baseline: 1.0462x; 1.0347x over previous
//
#include <hip/hip_runtime.h>

typedef unsigned short u16;
typedef unsigned int u32;
typedef __bf16 bf16x8 __attribute__((ext_vector_type(8)));
typedef float f32x4 __attribute__((ext_vector_type(4)));
typedef float f32x16 __attribute__((ext_vector_type(16)));
typedef u32 u32x4 __attribute__((ext_vector_type(4)));

#define MFMA_BF16(a, b, c) __builtin_amdgcn_mfma_f32_16x16x32_bf16((a), (b), (c), 0, 0, 0)
#define MFMA32(a, b, c) __builtin_amdgcn_mfma_f32_32x32x16_bf16((a), (b), (c), 0, 0, 0)

// log2-domain constant: 0.125 * log2(e), folded into w_qkv Q-rows at prep
#define QSCALE 0.18033688011112042f

#define BARRIER __builtin_amdgcn_s_barrier()
#define LGKM0                                                \
  do {                                                       \
    asm volatile("s_waitcnt lgkmcnt(0)" ::: "memory");       \
    __builtin_amdgcn_sched_barrier(0);                       \
  } while (0)
#define WAIT_VM(N) asm volatile("s_waitcnt vmcnt(" #N ")" ::: "memory")

// ---------- helpers ----------

__device__ __forceinline__ u16 f2bf(float f) {
  u32 u = __builtin_bit_cast(u32, f);
  u += 0x7fffu + ((u >> 16) & 1u);   // RNE
  return (u16)(u >> 16);
}

__device__ __forceinline__ void async_copy16(const void* g, void* l) {
  __builtin_amdgcn_global_load_lds(
      (__attribute__((address_space(1))) void*)g,
      (__attribute__((address_space(3))) void*)l, 16, 0, 0);
}

__device__ __forceinline__ u32 cvt_pk_bf16(float lo, float hi) {
  u32 d;
  asm("v_cvt_pk_bf16_f32 %0, %1, %2" : "=v"(d) : "v"(lo), "v"(hi));
  return d;
}

__device__ __forceinline__ void swap32(u32& a, u32& b) {
  asm("v_permlane32_swap_b32 %0, %1" : "+v"(a), "+v"(b));
}

// ---------- kernel 0: fused fp32->bf16 converts + RoPE cos/sin table ----------

__global__ __launch_bounds__(256) void prep_kernel(
    const float* __restrict__ x_f, const float* __restrict__ wqkv_f,
    const float* __restrict__ wo_f, u16* __restrict__ xb,
    u16* __restrict__ wqkvb, u16* __restrict__ wob, float2* __restrict__ rope_t) {
  const int blk = blockIdx.x;
  if (blk < 12288) {
    const float* src;
    u16* dst;
    int base;
    float scale = 1.0f;
    if (blk < 8192)      { src = x_f;    dst = xb;    base = blk; }
    else if (blk < 11264){ src = wqkv_f; dst = wqkvb; base = blk - 8192;
                           if (base < 1024) scale = QSCALE; }  // Q rows
    else                 { src = wo_f;   dst = wob;   base = blk - 11264; }
    const int i = base * 1024 + threadIdx.x * 4;
    const float4 v = *(const float4*)(src + i);
    ushort4 o;
    o.x = f2bf(v.x * scale); o.y = f2bf(v.y * scale);
    o.z = f2bf(v.z * scale); o.w = f2bf(v.w * scale);
    *(ushort4*)(dst + i) = o;
  } else {
    const int idx = (blk - 12288) * 256 + threadIdx.x;  // [0, 65536)
    const int s = idx >> 5, i = idx & 31;
    const float invf = __builtin_amdgcn_exp2f(-(float)i * 0.41524101186092027f);
    float rev = (float)s * invf * 0.15915494309189535f;  // radians -> revolutions
    rev -= floorf(rev);
    rope_t[idx] = make_float2(__builtin_amdgcn_cosf(rev), __builtin_amdgcn_sinf(rev));
  }
}

// ---------- 256x128 GEMM-BT core (r2 structure, best measured on this shape) --
// 512 thr = 8 waves (4M x 2N); per-wave 64x64 = acc[4][4]; BK=64; 96 KB dbuf.
// 3 phases/K-tile (quadrant schedule), tile-end staging of t+2 with counted
// WAIT_VM(6) (never 0 mid-loop). XOR granule swizzle on source + read.

__device__ __forceinline__ void gemm256_bt(const u16* __restrict__ A,
                                           const u16* __restrict__ B,
                                           int row0, int col0, u16* lds,
                                           f32x4 acc[4][4]) {
  const int tid = threadIdx.x;
  const int wave = tid >> 6, lane = tid & 63;
  const int fr = lane & 15, quad = lane >> 4;
  const int wm = (wave >> 1) * 64;   // 0,64,128,192
  const int wn = (wave & 1) * 64;    // 0,64
  u16* bufA0 = lds;                  // [256][64]
  u16* bufB0 = lds + 16384;          // [128][64]
  u16* bufA1 = lds + 24576;
  u16* bufB1 = lds + 40960;

  const int l8 = lane >> 3, l7 = lane & 7;
  const int csw = (l7 ^ l8) * 8;     // pre-swizzled source col (l8 < 8)

  f32x4 zero = {0.f, 0.f, 0.f, 0.f};
#pragma unroll
  for (int mt = 0; mt < 4; ++mt)
#pragma unroll
    for (int nt = 0; nt < 4; ++nt) acc[mt][nt] = zero;

  auto stage = [&](int t) {
    u16* ba = (t & 1) ? bufA1 : bufA0;
    u16* bb = (t & 1) ? bufB1 : bufB0;
    const int k0 = t * 64;
#pragma unroll
    for (int c = 0; c < 4; ++c) {
      const int ch = c * 8 + wave;   // 0..31 -> rows [ch*8, ch*8+8)
      async_copy16(A + (size_t)(row0 + ch * 8 + l8) * 1024 + k0 + csw,
                   ba + ch * 512);
    }
#pragma unroll
    for (int c = 0; c < 2; ++c) {
      const int ch = c * 8 + wave;   // 0..15
      async_copy16(B + (size_t)(col0 + ch * 8 + l8) * 1024 + k0 + csw,
                   bb + ch * 512);
    }
  };

  const int f7 = fr & 7;
  const int sw0 = (quad ^ f7) * 8;         // kk = 0
  const int sw1 = ((quad + 4) ^ f7) * 8;   // kk = 1
  const int ar0 = (wm + fr) * 64, ar1 = (wm + 16 + fr) * 64;
  const int ar2 = (wm + 32 + fr) * 64, ar3 = (wm + 48 + fr) * 64;
  const int br0 = (wn + fr) * 64, br1 = (wn + 16 + fr) * 64;
  const int br2 = (wn + 32 + fr) * 64, br3 = (wn + 48 + fr) * 64;

  stage(0);
  stage(1);
  WAIT_VM(6);
  BARRIER;

  for (int t = 0; t < 16; ++t) {
    const u16* ba = (t & 1) ? bufA1 : bufA0;
    const u16* bb = (t & 1) ? bufB1 : bufB0;

    bf16x8 a0k0 = *(const bf16x8*)(ba + ar0 + sw0);
    bf16x8 a0k1 = *(const bf16x8*)(ba + ar0 + sw1);
    bf16x8 a1k0 = *(const bf16x8*)(ba + ar1 + sw0);
    bf16x8 a1k1 = *(const bf16x8*)(ba + ar1 + sw1);
    bf16x8 b0k0 = *(const bf16x8*)(bb + br0 + sw0);
    bf16x8 b0k1 = *(const bf16x8*)(bb + br0 + sw1);
    bf16x8 b1k0 = *(const bf16x8*)(bb + br1 + sw0);
    bf16x8 b1k1 = *(const bf16x8*)(bb + br1 + sw1);
    BARRIER;
    LGKM0;
    __builtin_amdgcn_s_setprio(1);
    acc[0][0] = MFMA_BF16(a0k0, b0k0, acc[0][0]);
    acc[0][1] = MFMA_BF16(a0k0, b1k0, acc[0][1]);
    acc[1][0] = MFMA_BF16(a1k0, b0k0, acc[1][0]);
    acc[1][1] = MFMA_BF16(a1k0, b1k0, acc[1][1]);
    acc[0][0] = MFMA_BF16(a0k1, b0k1, acc[0][0]);
    acc[0][1] = MFMA_BF16(a0k1, b1k1, acc[0][1]);
    acc[1][0] = MFMA_BF16(a1k1, b0k1, acc[1][0]);
    acc[1][1] = MFMA_BF16(a1k1, b1k1, acc[1][1]);
    __builtin_amdgcn_s_setprio(0);
    BARRIER;

    bf16x8 b2k0 = *(const bf16x8*)(bb + br2 + sw0);
    bf16x8 b2k1 = *(const bf16x8*)(bb + br2 + sw1);
    bf16x8 b3k0 = *(const bf16x8*)(bb + br3 + sw0);
    bf16x8 b3k1 = *(const bf16x8*)(bb + br3 + sw1);
    BARRIER;
    LGKM0;
    __builtin_amdgcn_s_setprio(1);
    acc[0][2] = MFMA_BF16(a0k0, b2k0, acc[0][2]);
    acc[0][3] = MFMA_BF16(a0k0, b3k0, acc[0][3]);
    acc[1][2] = MFMA_BF16(a1k0, b2k0, acc[1][2]);
    acc[1][3] = MFMA_BF16(a1k0, b3k0, acc[1][3]);
    acc[0][2] = MFMA_BF16(a0k1, b2k1, acc[0][2]);
    acc[0][3] = MFMA_BF16(a0k1, b3k1, acc[0][3]);
    acc[1][2] = MFMA_BF16(a1k1, b2k1, acc[1][2]);
    acc[1][3] = MFMA_BF16(a1k1, b3k1, acc[1][3]);
    __builtin_amdgcn_s_setprio(0);
    BARRIER;

    bf16x8 a2k0 = *(const bf16x8*)(ba + ar2 + sw0);
    bf16x8 a2k1 = *(const bf16x8*)(ba + ar2 + sw1);
    bf16x8 a3k0 = *(const bf16x8*)(ba + ar3 + sw0);
    bf16x8 a3k1 = *(const bf16x8*)(ba + ar3 + sw1);
    BARRIER;
    LGKM0;
    __builtin_amdgcn_s_setprio(1);
    acc[2][0] = MFMA_BF16(a2k0, b0k0, acc[2][0]);
    acc[2][1] = MFMA_BF16(a2k0, b1k0, acc[2][1]);
    acc[3][0] = MFMA_BF16(a3k0, b0k0, acc[3][0]);
    acc[3][1] = MFMA_BF16(a3k0, b1k0, acc[3][1]);
    acc[2][0] = MFMA_BF16(a2k1, b0k1, acc[2][0]);
    acc[2][1] = MFMA_BF16(a2k1, b1k1, acc[2][1]);
    acc[3][0] = MFMA_BF16(a3k1, b0k1, acc[3][0]);
    acc[3][1] = MFMA_BF16(a3k1, b1k1, acc[3][1]);
    acc[2][2] = MFMA_BF16(a2k0, b2k0, acc[2][2]);
    acc[2][3] = MFMA_BF16(a2k0, b3k0, acc[2][3]);
    acc[3][2] = MFMA_BF16(a3k0, b2k0, acc[3][2]);
    acc[3][3] = MFMA_BF16(a3k0, b3k0, acc[3][3]);
    acc[2][2] = MFMA_BF16(a2k1, b2k1, acc[2][2]);
    acc[2][3] = MFMA_BF16(a2k1, b3k1, acc[2][3]);
    acc[3][2] = MFMA_BF16(a3k1, b2k1, acc[3][2]);
    acc[3][3] = MFMA_BF16(a3k1, b3k1, acc[3][3]);
    __builtin_amdgcn_s_setprio(0);

    BARRIER;
    if (t + 2 < 16) {
      stage(t + 2);
      WAIT_VM(6);
    } else if (t + 2 == 16) {
      WAIT_VM(0);
    }
    BARRIER;
  }
}

// ---------- kernel 1: QKV projection + RoPE (r2 structure) + XCD swizzle -----
// 256x128 tiles: grid (24, 32) = 768 blocks = 3 exact rounds.
// T1: XCD-chunked bijective remap (768 % 8 == 0): HW blocks id%8 -> XCD id%8;
// logical tile = (id&7)*96 + id>>3 gives each XCD a contiguous 96-tile chunk
// (4 row-panels x 24 cols) -> A-panel reuse hits that XCD's L2.

__global__ __launch_bounds__(512, 2) void qkv_rope_kernel(
    const u16* __restrict__ x, const u16* __restrict__ w_qkv,
    const float2* __restrict__ rope_t,
    u16* __restrict__ q_ws, u16* __restrict__ k_ws, u16* __restrict__ vt_ws) {
  __shared__ u16 lds[49152];  // 96 KB: gemm dbuf; epilogue reuses it
  f32x4 acc[4][4];
  const int lin0 = blockIdx.x + 24 * blockIdx.y;   // 0..767
  const int lin = (lin0 & 7) * 96 + (lin0 >> 3);   // bijective XCD-chunk remap
  const int row0 = (lin / 24) * 256;  // M = 8192
  const int col0 = (lin % 24) * 128;  // N = 3072
  gemm256_bt(x, w_qkv, row0, col0, lds, acc);

  const int tid = threadIdx.x;
  const int wave = tid >> 6, lane = tid & 63;
  const int fr = lane & 15, quad = lane >> 4;
  const int wm = (wave >> 1) * 64, wn = (wave & 1) * 64;
  const int region = col0 >> 10;      // 0=Q 1=K 2=V (block-uniform; 1024%128==0)
  const int f0 = col0 & 1023;
  const int s0r = row0 & 2047;
  const int bb = row0 >> 11;
  const int h0 = f0 >> 6;             // block covers heads h0, h0+1

  if (region < 2) {
    // rotate in registers, stage [m 256][n 128] (stride 136)
#pragma unroll
    for (int mt = 0; mt < 4; ++mt) {
#pragma unroll
      for (int nt = 0; nt < 4; ++nt) {
        const int n = wn + nt * 16 + fr;
        const int d = n & 63;  // col0/wn are 64-aligned
#pragma unroll
        for (int r = 0; r < 4; ++r) {
          const int m = wm + mt * 16 + quad * 4 + r;
          const float own = acc[mt][nt][r];
          const float part = __shfl_xor(own, 1);
          const int s = s0r + m;
          const float2 cssn = rope_t[s * 32 + (d >> 1)];
          const float val = (d & 1) ? (part * cssn.y + own * cssn.x)
                                    : (own * cssn.x - part * cssn.y);
          lds[m * 136 + n] = f2bf(val);
        }
      }
    }
    __syncthreads();
    u16* dst = (region == 0) ? q_ws : k_ws;
#pragma unroll
    for (int j = 0; j < 8; ++j) {
      const int idx2 = j * 512 + tid;       // 0..4095
      const int m = idx2 >> 4;              // 0..255
      const int rem = idx2 & 15;
      const int hf = rem >> 3;              // head half (0/1)
      const int c8 = (rem & 7) * 8;
      const uint4 v = *(const uint4*)(lds + m * 136 + hf * 64 + c8);
      *(uint4*)(dst + ((size_t)(bb * 16 + h0 + hf) * 2048 + s0r + m) * 64 + c8) = v;
    }
  } else {
    // stage transposed [n 128][m 256] (stride 264)
#pragma unroll
    for (int mt = 0; mt < 4; ++mt)
#pragma unroll
      for (int nt = 0; nt < 4; ++nt) {
        const int n = wn + nt * 16 + fr;
#pragma unroll
        for (int r = 0; r < 4; ++r) {
          const int m = wm + mt * 16 + quad * 4 + r;
          lds[n * 264 + m] = f2bf(acc[mt][nt][r]);
        }
      }
    __syncthreads();
#pragma unroll
    for (int j = 0; j < 8; ++j) {
      const int idx2 = j * 512 + tid;       // 0..4095
      const int n = idx2 >> 5;              // 0..127
      const int mc = (idx2 & 31) * 8;       // 0..248
      const int h = h0 + (n >> 6);
      const int d = n & 63;
      const uint4 v = *(const uint4*)(lds + n * 264 + mc);
      *(uint4*)(vt_ws + ((size_t)(bb * 16 + h) * 64 + d) * 2048 + s0r + mc) = v;
    }
  }
}

// ---------- kernel 2: causal flash attention, swapped-QK 32x32 in-reg softmax -
// (verified r3 structure, unchanged)

__global__ __launch_bounds__(256, 3) void flash_attn_kernel(
    const u16* __restrict__ Q, const u16* __restrict__ K, const u16* __restrict__ Vt,
    const int* __restrict__ pad, u16* __restrict__ O) {
  const int S = 2048;
  const int idx = blockIdx.x;
  const int bh = idx & 63;
  const int b = bh >> 4, h = bh & 15;
  // balanced q-tile remap: perm = [[0,1,2,3],[7,6,5,4],[8,9,10,11],[15,14,13,12]]
  const int j = (idx >> 6) & 3;
  const int sr = idx >> 8;
  const int qt_rev = (sr >> 1) * 8 + ((sr & 1) ? (7 - j) : j);
  const int q0 = (15 - qt_rev) * 128;
  const u16* Qh = Q + (size_t)bh * S * 64;
  const u16* Kh = K + (size_t)bh * S * 64;
  const u16* Vth = Vt + (size_t)bh * 64 * S;
  const int tid = threadIdx.x, wave = tid >> 6, lane = tid & 63;
  const int l31 = lane & 31, hi = lane >> 5, l7 = lane & 7;

  __shared__ u16 lds_k[2][64 * 64];    // dbuf [kpos 64][d 64] swizzled  16 KB
  __shared__ u16 lds_vt[2][64 * 64];   // dbuf [d 64][kpos 64] swizzled  16 KB
  __shared__ float lds_biasf[2][64];   // {0, -inf} per kpos             512 B

  const int qb = q0 + wave * 32;  // wave's first q row

  // Q as B-operand: lane holds Q[qb + l31][d = c*16 + hi*8 + 0..7]
  bf16x8 qfrag[4];
#pragma unroll
  for (int c = 0; c < 4; ++c)
    qfrag[c] = *(const bf16x8*)(Qh + (size_t)(qb + l31) * 64 + c * 16 + hi * 8);

  bf16x8 ones;
#pragma unroll
  for (int jj = 0; jj < 8; ++jj) ones[jj] = (__bf16)1.0f;

  f32x16 o_acc0, o_acc1, lacc;
#pragma unroll
  for (int r = 0; r < 16; ++r) { o_acc0[r] = 0.f; o_acc1[r] = 0.f; lacc[r] = 0.f; }

  const float NEG = -__builtin_inff();
  int pv0 = 1, pv1 = 1;

  auto stage = [&](int k0, int bufi) {
#pragma unroll
    for (int it = 0; it < 2; ++it) {
      const int slot = it * 256 + tid;   // 0..511
      const int row = slot >> 3;         // 0..63
      const int g = slot & 7;
      const int gs = (g ^ (row & 7)) * 8;  // inverse-swizzled source granule
      async_copy16(Kh + (size_t)(k0 + row) * 64 + gs, &lds_k[bufi][slot * 8]);
      async_copy16(Vth + (size_t)row * 2048 + k0 + gs, &lds_vt[bufi][slot * 8]);
    }
    if (tid < 64) lds_biasf[bufi][tid] = pad[b * S + k0 + tid] ? 0.f : NEG;
    const int pvn = pad[b * S + k0 + lane];   // per-wave ballot source
    if (bufi) pv1 = pvn; else pv0 = pvn;
  };

  const int kend = q0 + 64;  // last k-tile origin (inclusive)
  stage(0, 0);
  __syncthreads();  // drains vmcnt(0): tile 0 resident
  int cur = 0;

  for (int k0 = 0; k0 <= kend; k0 += 64) {
    if (k0 < kend) stage(k0 + 64, cur ^ 1);  // prefetch next tile

    if (k0 <= qb + 31) {  // wave-uniform: skip fully-masked tiles
      const u16* lk = lds_k[cur];
      const u16* lvt = lds_vt[cur];
      const float* lb = lds_biasf[cur];
      const int pvc = cur ? pv1 : pv0;
      const bool fast = (__ballot(pvc != 0) == ~0ull);
      const bool needMask = (k0 + 63 > qb);
      const int thrh = qb + l31 - k0 - 4 * hi;  // mask iff rm+32*kt > thrh

      // ---- QK^T swapped: S[kpos][q], kpos reg-mapped, q = l31 ----
      f32x16 sacc0, sacc1;
#pragma unroll
      for (int r = 0; r < 16; ++r) { sacc0[r] = 0.f; sacc1[r] = 0.f; }
#pragma unroll
      for (int c = 0; c < 4; ++c) {
        const int gsw = ((2 * c + hi) ^ l7) * 8;
        bf16x8 kf0 = *(const bf16x8*)(lk + l31 * 64 + gsw);
        bf16x8 kf1 = *(const bf16x8*)(lk + (l31 + 32) * 64 + gsw);
        sacc0 = MFMA32(kf0, qfrag[c], sacc0);
        sacc1 = MFMA32(kf1, qfrag[c], sacc1);
      }

      // ---- softmax in-register + pack to PV A-frags ----
      bf16x8 pa[2][2];
#pragma unroll
      for (int kt = 0; kt < 2; ++kt) {
        float pe[16];
        if (fast) {
#pragma unroll
          for (int r = 0; r < 16; ++r) {
            float s = (kt == 0) ? sacc0[r] : sacc1[r];
            if (needMask) {
              const int rm = (r & 3) + 8 * (r >> 2) + 32 * kt;
              s = (rm > thrh) ? NEG : s;
            }
            pe[r] = __builtin_amdgcn_exp2f(s);
          }
        } else {
          f32x4 bv[4];
#pragma unroll
          for (int g = 0; g < 4; ++g)
            bv[g] = *(const f32x4*)(lb + g * 8 + 4 * hi + 32 * kt);
#pragma unroll
          for (int r = 0; r < 16; ++r) {
            float s = ((kt == 0) ? sacc0[r] : sacc1[r]) + bv[r >> 2][r & 3];
            if (needMask) {
              const int rm = (r & 3) + 8 * (r >> 2) + 32 * kt;
              s = (rm > thrh) ? NEG : s;
            }
            pe[r] = __builtin_amdgcn_exp2f(s);
          }
        }
        u32 a0 = cvt_pk_bf16(pe[0], pe[1]), a1 = cvt_pk_bf16(pe[2], pe[3]);
        u32 b0 = cvt_pk_bf16(pe[4], pe[5]), b1 = cvt_pk_bf16(pe[6], pe[7]);
        swap32(a0, b0);
        swap32(a1, b1);
        u32x4 w0 = {a0, a1, b0, b1};
        pa[kt][0] = __builtin_bit_cast(bf16x8, w0);
        u32 c0 = cvt_pk_bf16(pe[8], pe[9]), c1 = cvt_pk_bf16(pe[10], pe[11]);
        u32 d0 = cvt_pk_bf16(pe[12], pe[13]), d1 = cvt_pk_bf16(pe[14], pe[15]);
        swap32(c0, d0);
        swap32(c1, d1);
        u32x4 w1 = {c0, c1, d0, d1};
        pa[kt][1] = __builtin_bit_cast(bf16x8, w1);
      }

      // ---- PV + row-sum: O[q][d] and l[q], q reg-mapped ----
      __builtin_amdgcn_s_setprio(1);
#pragma unroll
      for (int kt = 0; kt < 2; ++kt)
#pragma unroll
        for (int ks = 0; ks < 2; ++ks) {
          const int kq = kt * 2 + ks;
          lacc = MFMA32(pa[kt][ks], ones, lacc);
          const int gsw = ((2 * kq + hi) ^ l7) * 8;
          bf16x8 vf0 = *(const bf16x8*)(lvt + l31 * 64 + gsw);
          bf16x8 vf1 = *(const bf16x8*)(lvt + (l31 + 32) * 64 + gsw);
          o_acc0 = MFMA32(pa[kt][ks], vf0, o_acc0);
          o_acc1 = MFMA32(pa[kt][ks], vf1, o_acc1);
        }
      __builtin_amdgcn_s_setprio(0);
    }

    __syncthreads();  // drains vmcnt(0) (prefetch landed) + all reads of cur done
    cur ^= 1;
  }

  // epilogue: normalize, write [B][S][H*64]
#pragma unroll
  for (int r = 0; r < 16; ++r) {
    const int q = qb + (r & 3) + 8 * (r >> 2) + 4 * hi;
    const float l = lacc[r];
    const float rl = (l > 0.f) ? (1.0f / l) : 0.f;
    O[(size_t)(b * S + q) * 1024 + h * 64 + l31] = f2bf(o_acc0[r] * rl);
    O[(size_t)(b * S + q) * 1024 + h * 64 + 32 + l31] = f2bf(o_acc1[r] * rl);
  }
}

// ---------- kernel 3: output projection (writes fp32 to d_out) ----------

__global__ __launch_bounds__(512, 2) void oproj_kernel(
    const u16* __restrict__ A, const u16* __restrict__ w_o, float* __restrict__ out) {
  __shared__ u16 lds[49152];
  f32x4 acc[4][4];
  const int row0 = blockIdx.y * 256;
  const int col0 = blockIdx.x * 128;
  gemm256_bt(A, w_o, row0, col0, lds, acc);
  const int tid = threadIdx.x;
  const int wave = tid >> 6, lane = tid & 63;
  const int fr = lane & 15, quad = lane >> 4;
  const int wm = (wave >> 1) * 64, wn = (wave & 1) * 64;
#pragma unroll
  for (int mt = 0; mt < 4; ++mt)
#pragma unroll
    for (int nt = 0; nt < 4; ++nt) {
      const int ncol = col0 + wn + nt * 16 + fr;
#pragma unroll
      for (int r = 0; r < 4; ++r) {
        const int mrow = row0 + wm + mt * 16 + quad * 4 + r;
        out[(size_t)mrow * 1024 + ncol] = acc[mt][nt][r];
      }
    }
}

// ---------- launch ----------

extern "C" void kernel_launch(void* const* d_in, const int* in_sizes, int n_in,
                              void* d_out, int out_size, void* d_ws, size_t ws_size,
                              hipStream_t stream) {
  const float* x_f = (const float*)d_in[0];     // [4][2048][1024] fp32
  const int* pad = (const int*)d_in[1];         // [4][2048] int32
  const float* wqkv_f = (const float*)d_in[2];  // [3072][1024] fp32
  const float* wo_f = (const float*)d_in[3];    // [1024][1024] fp32
  float* out = (float*)d_out;                   // [4][2048][1024] fp32

  const int NX = 4 * 2048 * 1024;
  const int NWQKV = 3072 * 1024;
  const int NWO = 1024 * 1024;
  const size_t HSZ = (size_t)4 * 16 * 2048 * 64;  // 8M elems per head-tensor

  u16* xb = (u16*)d_ws;            // 16 MB
  u16* wqkvb = xb + NX;            // 6 MB
  u16* wob = wqkvb + NWQKV;        // 2 MB
  u16* q_ws = wob + NWO;           // 16 MB  [B][H][S][64] (pre-scaled, roped)
  u16* k_ws = q_ws + HSZ;          // 16 MB  [B][H][S][64] (roped)
  u16* vt_ws = k_ws + HSZ;         // 16 MB  [B][H][64][S] (transposed)
  u16* attn_ws = vt_ws + HSZ;      // 16 MB  [B*S][D]
  float2* rope_t = (float2*)(attn_ws + HSZ);  // 512 KB [2048][32]

  prep_kernel<<<dim3(12544), dim3(256), 0, stream>>>(x_f, wqkv_f, wo_f, xb, wqkvb,
                                                     wob, rope_t);
  qkv_rope_kernel<<<dim3(24, 32), dim3(512), 0, stream>>>(xb, wqkvb, rope_t, q_ws,
                                                          k_ws, vt_ws);
  flash_attn_kernel<<<dim3(1024), dim3(256), 0, stream>>>(q_ws, k_ws, vt_ws, pad,
                                                          attn_ws);
  oproj_kernel<<<dim3(8, 32), dim3(512), 0, stream>>>(attn_ws, wob, out);
}

// Round 9
// 243.942 us; speedup vs baseline: 1.0860x; 1.0381x over previous
//
#include <hip/hip_runtime.h>

typedef unsigned short u16;
typedef unsigned int u32;
typedef __bf16 bf16x8 __attribute__((ext_vector_type(8)));
typedef float f32x4 __attribute__((ext_vector_type(4)));
typedef float f32x16 __attribute__((ext_vector_type(16)));
typedef u32 u32x4 __attribute__((ext_vector_type(4)));

#define MFMA_BF16(a, b, c) __builtin_amdgcn_mfma_f32_16x16x32_bf16((a), (b), (c), 0, 0, 0)
#define MFMA32(a, b, c) __builtin_amdgcn_mfma_f32_32x32x16_bf16((a), (b), (c), 0, 0, 0)

// log2-domain constant: 0.125 * log2(e), folded into w_qkv Q-rows at prep
#define QSCALE 0.18033688011112042f

#define BARRIER __builtin_amdgcn_s_barrier()
#define LGKM0                                                \
  do {                                                       \
    asm volatile("s_waitcnt lgkmcnt(0)" ::: "memory");       \
    __builtin_amdgcn_sched_barrier(0);                       \
  } while (0)
#define WAIT_VM(N) asm volatile("s_waitcnt vmcnt(" #N ")" ::: "memory")

// ---------- helpers ----------

__device__ __forceinline__ u16 f2bf(float f) {
  u32 u = __builtin_bit_cast(u32, f);
  u += 0x7fffu + ((u >> 16) & 1u);   // RNE
  return (u16)(u >> 16);
}

__device__ __forceinline__ void async_copy16(const void* g, void* l) {
  __builtin_amdgcn_global_load_lds(
      (__attribute__((address_space(1))) void*)g,
      (__attribute__((address_space(3))) void*)l, 16, 0, 0);
}

__device__ __forceinline__ u32 cvt_pk_bf16(float lo, float hi) {
  u32 d;
  asm("v_cvt_pk_bf16_f32 %0, %1, %2" : "=v"(d) : "v"(lo), "v"(hi));
  return d;
}

__device__ __forceinline__ void swap32(u32& a, u32& b) {
  asm("v_permlane32_swap_b32 %0, %1" : "+v"(a), "+v"(b));
}

// ---------- kernel 0: fused fp32->bf16 converts + RoPE cos/sin table ----------

__global__ __launch_bounds__(256) void prep_kernel(
    const float* __restrict__ x_f, const float* __restrict__ wqkv_f,
    const float* __restrict__ wo_f, u16* __restrict__ xb,
    u16* __restrict__ wqkvb, u16* __restrict__ wob, float2* __restrict__ rope_t) {
  const int blk = blockIdx.x;
  if (blk < 12288) {
    const float* src;
    u16* dst;
    int base;
    float scale = 1.0f;
    if (blk < 8192)      { src = x_f;    dst = xb;    base = blk; }
    else if (blk < 11264){ src = wqkv_f; dst = wqkvb; base = blk - 8192;
                           if (base < 1024) scale = QSCALE; }  // Q rows
    else                 { src = wo_f;   dst = wob;   base = blk - 11264; }
    const int i = base * 1024 + threadIdx.x * 4;
    const float4 v = *(const float4*)(src + i);
    ushort4 o;
    o.x = f2bf(v.x * scale); o.y = f2bf(v.y * scale);
    o.z = f2bf(v.z * scale); o.w = f2bf(v.w * scale);
    *(ushort4*)(dst + i) = o;
  } else {
    const int idx = (blk - 12288) * 256 + threadIdx.x;  // [0, 65536)
    const int s = idx >> 5, i = idx & 31;
    const float invf = __builtin_amdgcn_exp2f(-(float)i * 0.41524101186092027f);
    float rev = (float)s * invf * 0.15915494309189535f;  // radians -> revolutions
    rev -= floorf(rev);
    rope_t[idx] = make_float2(__builtin_amdgcn_cosf(rev), __builtin_amdgcn_sinf(rev));
  }
}

// ---------- 256x128 GEMM-BT core, BK=32 TRIPLE-buffer, 1 barrier/K-step ------
// 512 thr = 8 waves (4M x 2N); per-wave 64x64 = acc[4][4]; BK=32.
// LDS: 3 bufs x (A[256][32] 16KB + B[128][32] 8KB) = 72 KB -> 2 blocks/CU
// (16 waves/CU = 4/SIMD -- the cross-wave overlap m97-class rates need).
// Triple buffer: stage(t+2) targets buf (t+2)%3, disjoint from the buffer
// being read (t%3) and the next (t+1)%3 -> staging issues right after the
// ds_reads with NO extra barrier. One barrier per K-step.
// Counted WAIT_VM(3): t+1's 3 loads retired, t+2's 3 stay in flight.
// BK=32 rows are 64B; a wave's 4xds_read_b128 covers 16 rows x 64B = 1KB
// contiguous -> naturally conflict-free, no swizzle needed.

__device__ __forceinline__ void gemm_tb(const u16* __restrict__ A,
                                        const u16* __restrict__ B,
                                        int row0, int col0, u16* lds,
                                        f32x4 acc[4][4]) {
  const int tid = threadIdx.x;
  const int wave = tid >> 6, lane = tid & 63;
  const int fr = lane & 15, quad = lane >> 4;
  const int wm = (wave >> 1) * 64;   // 0,64,128,192
  const int wn = (wave & 1) * 64;    // 0,64

  f32x4 zero = {0.f, 0.f, 0.f, 0.f};
#pragma unroll
  for (int mt = 0; mt < 4; ++mt)
#pragma unroll
    for (int nt = 0; nt < 4; ++nt) acc[mt][nt] = zero;

  // stage K-step t into buf t%3: A 2 insts + B 1 inst per thread
  auto stage = [&](int t) {
    u16* base = lds + (t % 3) * 12288;
    const int k0 = t * 32;
#pragma unroll
    for (int it = 0; it < 2; ++it) {
      const int slot = it * 512 + tid;   // 0..1023
      const int row = slot >> 2, g = slot & 3;
      async_copy16(A + (size_t)(row0 + row) * 1024 + k0 + g * 8, base + slot * 8);
    }
    const int row = tid >> 2, g = tid & 3;
    async_copy16(B + (size_t)(col0 + row) * 1024 + k0 + g * 8,
                 base + 8192 + tid * 8);
  };

  const int aoff = fr * 32 + quad * 8;   // within-A row/frag offset
  stage(0);
  stage(1);
  WAIT_VM(3);   // step 0's 3 loads landed
  BARRIER;

  for (int t = 0; t < 32; ++t) {
    const u16* bs = lds + (t % 3) * 12288;

    bf16x8 a[4], b[4];
#pragma unroll
    for (int m = 0; m < 4; ++m)
      a[m] = *(const bf16x8*)(bs + (wm + m * 16) * 32 + aoff);
#pragma unroll
    for (int n = 0; n < 4; ++n)
      b[n] = *(const bf16x8*)(bs + 8192 + (wn + n * 16) * 32 + aoff);

    if (t + 2 < 32) stage(t + 2);   // disjoint buf: no WAR with current reads

    LGKM0;
    __builtin_amdgcn_s_setprio(1);
#pragma unroll
    for (int m = 0; m < 4; ++m)
#pragma unroll
      for (int n = 0; n < 4; ++n)
        acc[m][n] = MFMA_BF16(a[m], b[n], acc[m][n]);
    __builtin_amdgcn_s_setprio(0);

    if (t + 2 < 32) { WAIT_VM(3); } else { WAIT_VM(0); }  // t+1 resident
    BARRIER;
  }
}

// ---------- kernel 1: QKV projection + RoPE (epilogue unchanged) -------------
// 256x128 tiles: grid (24, 32) = 768 blocks at 2 blocks/CU.
// XCD-chunked bijective remap (768 % 8 == 0) kept from r7.

__global__ __launch_bounds__(512, 4) void qkv_rope_kernel(
    const u16* __restrict__ x, const u16* __restrict__ w_qkv,
    const float2* __restrict__ rope_t,
    u16* __restrict__ q_ws, u16* __restrict__ k_ws, u16* __restrict__ vt_ws) {
  __shared__ u16 lds[36864];  // 72 KB: gemm triple-buf; epilogue reuses it
  f32x4 acc[4][4];
  const int lin0 = blockIdx.x + 24 * blockIdx.y;   // 0..767
  const int lin = (lin0 & 7) * 96 + (lin0 >> 3);   // bijective XCD-chunk remap
  const int row0 = (lin / 24) * 256;  // M = 8192
  const int col0 = (lin % 24) * 128;  // N = 3072
  gemm_tb(x, w_qkv, row0, col0, lds, acc);

  const int tid = threadIdx.x;
  const int wave = tid >> 6, lane = tid & 63;
  const int fr = lane & 15, quad = lane >> 4;
  const int wm = (wave >> 1) * 64, wn = (wave & 1) * 64;
  const int region = col0 >> 10;      // 0=Q 1=K 2=V (block-uniform; 1024%128==0)
  const int f0 = col0 & 1023;
  const int s0r = row0 & 2047;
  const int bb = row0 >> 11;
  const int h0 = f0 >> 6;             // block covers heads h0, h0+1

  if (region < 2) {
    // rotate in registers, stage [m 256][n 128] (stride 136)
#pragma unroll
    for (int mt = 0; mt < 4; ++mt) {
#pragma unroll
      for (int nt = 0; nt < 4; ++nt) {
        const int n = wn + nt * 16 + fr;
        const int d = n & 63;  // col0/wn are 64-aligned
#pragma unroll
        for (int r = 0; r < 4; ++r) {
          const int m = wm + mt * 16 + quad * 4 + r;
          const float own = acc[mt][nt][r];
          const float part = __shfl_xor(own, 1);
          const int s = s0r + m;
          const float2 cssn = rope_t[s * 32 + (d >> 1)];
          const float val = (d & 1) ? (part * cssn.y + own * cssn.x)
                                    : (own * cssn.x - part * cssn.y);
          lds[m * 136 + n] = f2bf(val);
        }
      }
    }
    __syncthreads();
    u16* dst = (region == 0) ? q_ws : k_ws;
#pragma unroll
    for (int j = 0; j < 8; ++j) {
      const int idx2 = j * 512 + tid;       // 0..4095
      const int m = idx2 >> 4;              // 0..255
      const int rem = idx2 & 15;
      const int hf = rem >> 3;              // head half (0/1)
      const int c8 = (rem & 7) * 8;
      const uint4 v = *(const uint4*)(lds + m * 136 + hf * 64 + c8);
      *(uint4*)(dst + ((size_t)(bb * 16 + h0 + hf) * 2048 + s0r + m) * 64 + c8) = v;
    }
  } else {
    // stage transposed [n 128][m 256] (stride 264)
#pragma unroll
    for (int mt = 0; mt < 4; ++mt)
#pragma unroll
      for (int nt = 0; nt < 4; ++nt) {
        const int n = wn + nt * 16 + fr;
#pragma unroll
        for (int r = 0; r < 4; ++r) {
          const int m = wm + mt * 16 + quad * 4 + r;
          lds[n * 264 + m] = f2bf(acc[mt][nt][r]);
        }
      }
    __syncthreads();
#pragma unroll
    for (int j = 0; j < 8; ++j) {
      const int idx2 = j * 512 + tid;       // 0..4095
      const int n = idx2 >> 5;              // 0..127
      const int mc = (idx2 & 31) * 8;       // 0..248
      const int h = h0 + (n >> 6);
      const int d = n & 63;
      const uint4 v = *(const uint4*)(lds + n * 264 + mc);
      *(uint4*)(vt_ws + ((size_t)(bb * 16 + h) * 64 + d) * 2048 + s0r + mc) = v;
    }
  }
}

// ---------- kernel 2: causal flash attention, swapped-QK 32x32 in-reg softmax -
// (verified r3 structure, unchanged)

__global__ __launch_bounds__(256, 3) void flash_attn_kernel(
    const u16* __restrict__ Q, const u16* __restrict__ K, const u16* __restrict__ Vt,
    const int* __restrict__ pad, u16* __restrict__ O) {
  const int S = 2048;
  const int idx = blockIdx.x;
  const int bh = idx & 63;
  const int b = bh >> 4, h = bh & 15;
  // balanced q-tile remap: perm = [[0,1,2,3],[7,6,5,4],[8,9,10,11],[15,14,13,12]]
  const int j = (idx >> 6) & 3;
  const int sr = idx >> 8;
  const int qt_rev = (sr >> 1) * 8 + ((sr & 1) ? (7 - j) : j);
  const int q0 = (15 - qt_rev) * 128;
  const u16* Qh = Q + (size_t)bh * S * 64;
  const u16* Kh = K + (size_t)bh * S * 64;
  const u16* Vth = Vt + (size_t)bh * 64 * S;
  const int tid = threadIdx.x, wave = tid >> 6, lane = tid & 63;
  const int l31 = lane & 31, hi = lane >> 5, l7 = lane & 7;

  __shared__ u16 lds_k[2][64 * 64];    // dbuf [kpos 64][d 64] swizzled  16 KB
  __shared__ u16 lds_vt[2][64 * 64];   // dbuf [d 64][kpos 64] swizzled  16 KB
  __shared__ float lds_biasf[2][64];   // {0, -inf} per kpos             512 B

  const int qb = q0 + wave * 32;  // wave's first q row

  // Q as B-operand: lane holds Q[qb + l31][d = c*16 + hi*8 + 0..7]
  bf16x8 qfrag[4];
#pragma unroll
  for (int c = 0; c < 4; ++c)
    qfrag[c] = *(const bf16x8*)(Qh + (size_t)(qb + l31) * 64 + c * 16 + hi * 8);

  bf16x8 ones;
#pragma unroll
  for (int jj = 0; jj < 8; ++jj) ones[jj] = (__bf16)1.0f;

  f32x16 o_acc0, o_acc1, lacc;
#pragma unroll
  for (int r = 0; r < 16; ++r) { o_acc0[r] = 0.f; o_acc1[r] = 0.f; lacc[r] = 0.f; }

  const float NEG = -__builtin_inff();
  int pv0 = 1, pv1 = 1;

  auto stage = [&](int k0, int bufi) {
#pragma unroll
    for (int it = 0; it < 2; ++it) {
      const int slot = it * 256 + tid;   // 0..511
      const int row = slot >> 3;         // 0..63
      const int g = slot & 7;
      const int gs = (g ^ (row & 7)) * 8;  // inverse-swizzled source granule
      async_copy16(Kh + (size_t)(k0 + row) * 64 + gs, &lds_k[bufi][slot * 8]);
      async_copy16(Vth + (size_t)row * 2048 + k0 + gs, &lds_vt[bufi][slot * 8]);
    }
    if (tid < 64) lds_biasf[bufi][tid] = pad[b * S + k0 + tid] ? 0.f : NEG;
    const int pvn = pad[b * S + k0 + lane];   // per-wave ballot source
    if (bufi) pv1 = pvn; else pv0 = pvn;
  };

  const int kend = q0 + 64;  // last k-tile origin (inclusive)
  stage(0, 0);
  __syncthreads();  // drains vmcnt(0): tile 0 resident
  int cur = 0;

  for (int k0 = 0; k0 <= kend; k0 += 64) {
    if (k0 < kend) stage(k0 + 64, cur ^ 1);  // prefetch next tile

    if (k0 <= qb + 31) {  // wave-uniform: skip fully-masked tiles
      const u16* lk = lds_k[cur];
      const u16* lvt = lds_vt[cur];
      const float* lb = lds_biasf[cur];
      const int pvc = cur ? pv1 : pv0;
      const bool fast = (__ballot(pvc != 0) == ~0ull);
      const bool needMask = (k0 + 63 > qb);
      const int thrh = qb + l31 - k0 - 4 * hi;  // mask iff rm+32*kt > thrh

      // ---- QK^T swapped: S[kpos][q], kpos reg-mapped, q = l31 ----
      f32x16 sacc0, sacc1;
#pragma unroll
      for (int r = 0; r < 16; ++r) { sacc0[r] = 0.f; sacc1[r] = 0.f; }
#pragma unroll
      for (int c = 0; c < 4; ++c) {
        const int gsw = ((2 * c + hi) ^ l7) * 8;
        bf16x8 kf0 = *(const bf16x8*)(lk + l31 * 64 + gsw);
        bf16x8 kf1 = *(const bf16x8*)(lk + (l31 + 32) * 64 + gsw);
        sacc0 = MFMA32(kf0, qfrag[c], sacc0);
        sacc1 = MFMA32(kf1, qfrag[c], sacc1);
      }

      // ---- softmax in-register + pack to PV A-frags ----
      bf16x8 pa[2][2];
#pragma unroll
      for (int kt = 0; kt < 2; ++kt) {
        float pe[16];
        if (fast) {
#pragma unroll
          for (int r = 0; r < 16; ++r) {
            float s = (kt == 0) ? sacc0[r] : sacc1[r];
            if (needMask) {
              const int rm = (r & 3) + 8 * (r >> 2) + 32 * kt;
              s = (rm > thrh) ? NEG : s;
            }
            pe[r] = __builtin_amdgcn_exp2f(s);
          }
        } else {
          f32x4 bv[4];
#pragma unroll
          for (int g = 0; g < 4; ++g)
            bv[g] = *(const f32x4*)(lb + g * 8 + 4 * hi + 32 * kt);
#pragma unroll
          for (int r = 0; r < 16; ++r) {
            float s = ((kt == 0) ? sacc0[r] : sacc1[r]) + bv[r >> 2][r & 3];
            if (needMask) {
              const int rm = (r & 3) + 8 * (r >> 2) + 32 * kt;
              s = (rm > thrh) ? NEG : s;
            }
            pe[r] = __builtin_amdgcn_exp2f(s);
          }
        }
        u32 a0 = cvt_pk_bf16(pe[0], pe[1]), a1 = cvt_pk_bf16(pe[2], pe[3]);
        u32 b0 = cvt_pk_bf16(pe[4], pe[5]), b1 = cvt_pk_bf16(pe[6], pe[7]);
        swap32(a0, b0);
        swap32(a1, b1);
        u32x4 w0 = {a0, a1, b0, b1};
        pa[kt][0] = __builtin_bit_cast(bf16x8, w0);
        u32 c0 = cvt_pk_bf16(pe[8], pe[9]), c1 = cvt_pk_bf16(pe[10], pe[11]);
        u32 d0 = cvt_pk_bf16(pe[12], pe[13]), d1 = cvt_pk_bf16(pe[14], pe[15]);
        swap32(c0, d0);
        swap32(c1, d1);
        u32x4 w1 = {c0, c1, d0, d1};
        pa[kt][1] = __builtin_bit_cast(bf16x8, w1);
      }

      // ---- PV + row-sum: O[q][d] and l[q], q reg-mapped ----
      __builtin_amdgcn_s_setprio(1);
#pragma unroll
      for (int kt = 0; kt < 2; ++kt)
#pragma unroll
        for (int ks = 0; ks < 2; ++ks) {
          const int kq = kt * 2 + ks;
          lacc = MFMA32(pa[kt][ks], ones, lacc);
          const int gsw = ((2 * kq + hi) ^ l7) * 8;
          bf16x8 vf0 = *(const bf16x8*)(lvt + l31 * 64 + gsw);
          bf16x8 vf1 = *(const bf16x8*)(lvt + (l31 + 32) * 64 + gsw);
          o_acc0 = MFMA32(pa[kt][ks], vf0, o_acc0);
          o_acc1 = MFMA32(pa[kt][ks], vf1, o_acc1);
        }
      __builtin_amdgcn_s_setprio(0);
    }

    __syncthreads();  // drains vmcnt(0) (prefetch landed) + all reads of cur done
    cur ^= 1;
  }

  // epilogue: normalize, write [B][S][H*64]
#pragma unroll
  for (int r = 0; r < 16; ++r) {
    const int q = qb + (r & 3) + 8 * (r >> 2) + 4 * hi;
    const float l = lacc[r];
    const float rl = (l > 0.f) ? (1.0f / l) : 0.f;
    O[(size_t)(b * S + q) * 1024 + h * 64 + l31] = f2bf(o_acc0[r] * rl);
    O[(size_t)(b * S + q) * 1024 + h * 64 + 32 + l31] = f2bf(o_acc1[r] * rl);
  }
}

// ---------- kernel 3: output projection (writes fp32 to d_out) ----------

__global__ __launch_bounds__(512, 4) void oproj_kernel(
    const u16* __restrict__ A, const u16* __restrict__ w_o, float* __restrict__ out) {
  __shared__ u16 lds[36864];
  f32x4 acc[4][4];
  const int row0 = blockIdx.y * 256;
  const int col0 = blockIdx.x * 128;
  gemm_tb(A, w_o, row0, col0, lds, acc);
  const int tid = threadIdx.x;
  const int wave = tid >> 6, lane = tid & 63;
  const int fr = lane & 15, quad = lane >> 4;
  const int wm = (wave >> 1) * 64, wn = (wave & 1) * 64;
#pragma unroll
  for (int mt = 0; mt < 4; ++mt)
#pragma unroll
    for (int nt = 0; nt < 4; ++nt) {
      const int ncol = col0 + wn + nt * 16 + fr;
#pragma unroll
      for (int r = 0; r < 4; ++r) {
        const int mrow = row0 + wm + mt * 16 + quad * 4 + r;
        out[(size_t)mrow * 1024 + ncol] = acc[mt][nt][r];
      }
    }
}

// ---------- launch ----------

extern "C" void kernel_launch(void* const* d_in, const int* in_sizes, int n_in,
                              void* d_out, int out_size, void* d_ws, size_t ws_size,
                              hipStream_t stream) {
  const float* x_f = (const float*)d_in[0];     // [4][2048][1024] fp32
  const int* pad = (const int*)d_in[1];         // [4][2048] int32
  const float* wqkv_f = (const float*)d_in[2];  // [3072][1024] fp32
  const float* wo_f = (const float*)d_in[3];    // [1024][1024] fp32
  float* out = (float*)d_out;                   // [4][2048][1024] fp32

  const int NX = 4 * 2048 * 1024;
  const int NWQKV = 3072 * 1024;
  const int NWO = 1024 * 1024;
  const size_t HSZ = (size_t)4 * 16 * 2048 * 64;  // 8M elems per head-tensor

  u16* xb = (u16*)d_ws;            // 16 MB
  u16* wqkvb = xb + NX;            // 6 MB
  u16* wob = wqkvb + NWQKV;        // 2 MB
  u16* q_ws = wob + NWO;           // 16 MB  [B][H][S][64] (pre-scaled, roped)
  u16* k_ws = q_ws + HSZ;          // 16 MB  [B][H][S][64] (roped)
  u16* vt_ws = k_ws + HSZ;         // 16 MB  [B][H][64][S] (transposed)
  u16* attn_ws = vt_ws + HSZ;      // 16 MB  [B*S][D]
  float2* rope_t = (float2*)(attn_ws + HSZ);  // 512 KB [2048][32]

  prep_kernel<<<dim3(12544), dim3(256), 0, stream>>>(x_f, wqkv_f, wo_f, xb, wqkvb,
                                                     wob, rope_t);
  qkv_rope_kernel<<<dim3(24, 32), dim3(512), 0, stream>>>(xb, wqkvb, rope_t, q_ws,
                                                          k_ws, vt_ws);
  flash_attn_kernel<<<dim3(1024), dim3(256), 0, stream>>>(q_ws, k_ws, vt_ws, pad,
                                                          attn_ws);
  oproj_kernel<<<dim3(8, 32), dim3(512), 0, stream>>>(attn_ws, wob, out);
}